// Round 4
// baseline (2134.135 us; speedup 1.0000x reference)
//
#include <hip/hip_runtime.h>
#include <stdint.h>

// GRUClassifier: 2-layer bidir GRU (H=128, T=512, B=512) + FC head.
// R4: hoist the input projection Gx = y0 @ W_ih^T out of the scan as a full
// GEMM (all 256 CUs), stored bf16 in a scan-friendly layout. The l1 scan then
// needs only W_hh fragments (48 VGPRs) -> fits 128 regs, no spills (R2/R3's
// 250-reg demand spilled ~120 regs every step; allocator refused >128).

#define Tt 512
#define Bb 512
#define THREADS 512

using s16x8 = __attribute__((ext_vector_type(8))) short;  // 8 bf16 (4 VGPRs)
using f32x4 = __attribute__((ext_vector_type(4))) float;

#define MF(a, b, c) __builtin_amdgcn_mfma_f32_16x16x32_bf16((a), (b), (c), 0, 0, 0)

__device__ __forceinline__ unsigned short f2bf(float f) {
    union { float f; unsigned int u; } v; v.f = f;
    unsigned int u = v.u;
    u += 0x7fffu + ((u >> 16) & 1u);   // RNE
    return (unsigned short)(u >> 16);
}
__device__ __forceinline__ float bf2f(unsigned short h) {
    union { unsigned int u; float f; } v; v.u = ((unsigned int)h) << 16;
    return v.f;
}

__device__ __forceinline__ float fsig(float x) {
    return __builtin_amdgcn_rcpf(1.0f + __expf(-x));
}
__device__ __forceinline__ float ftanh(float x) {
    return 2.0f * __builtin_amdgcn_rcpf(1.0f + __expf(-2.0f * x)) - 1.0f;
}

// Raw workgroup barrier: drains LDS ops only; in-flight global register
// prefetch loads survive it (vmcnt not drained).
#define WG_BARRIER() asm volatile("s_waitcnt lgkmcnt(0)\n\ts_barrier" ::: "memory")

// ---------------------------------------------------------------------------
// w_prep: pack W_ih (both dirs) to bf16 [768][256] + bias concat [768].
// ---------------------------------------------------------------------------
__global__ void w_prep(const float* __restrict__ wihf, const float* __restrict__ wihb,
                       const float* __restrict__ bihf, const float* __restrict__ bihb,
                       unsigned short* __restrict__ wcat, float* __restrict__ bcat)
{
    const int n = blockIdx.x;   // 0..767
    const int k = threadIdx.x;  // 0..255
    const float* src = (n < 384) ? &wihf[(size_t)n * 256] : &wihb[(size_t)(n - 384) * 256];
    wcat[(size_t)n * 256 + k] = f2bf(src[k]);
    if (k == 0) bcat[n] = (n < 384) ? bihf[n] : bihb[n - 384];
}

// ---------------------------------------------------------------------------
// gx_gemm: Gx[m][n] = y0[m][:] . Wcat[n][:] + bcat[n],  m=(t,b) 262144, n=768.
// 128x128 tiles, K=256 staged whole in LDS. Output bf16 in transposed layout:
// gx[t][dir][chunk(b>>4)][gc(0..383)][i(0..15)]  (gc = gate*128 + col).
// grid = 12288 (2048 m-tiles x 6 n-tiles), block = 256 (4 waves).
// ---------------------------------------------------------------------------
__global__ __launch_bounds__(256) void gx_gemm(
    const unsigned short* __restrict__ y0,
    const unsigned short* __restrict__ wcat,
    const float* __restrict__ bcat,
    unsigned short* __restrict__ gx)
{
    const int bx    = blockIdx.x;
    const int mtile = bx & 2047;        // 0..2047
    const int nt    = bx >> 11;         // 0..5
    const int t     = mtile >> 2;       // timestep
    const int bb    = (mtile & 3) << 7; // batch base (0,128,256,384)
    const int tid   = threadIdx.x;
    const int wave  = tid >> 6;
    const int lane  = tid & 63;
    const int lcol  = lane & 15;
    const int quad  = lane >> 4;

    __shared__ __align__(16) unsigned short lA[128][136];  // 34816 B
    __shared__ __align__(16) unsigned short lB[128][136];

    // stage A (y0 rows) and B (wcat rows), 16 B/thread/iter, coalesced
    {
        const unsigned short* Ab = y0 + ((size_t)t * 512 + bb) * 256;
        const unsigned short* Bbp = wcat + (size_t)nt * 128 * 256;
        const int r0 = tid >> 5, sgm = tid & 31;
#pragma unroll
        for (int it = 0; it < 16; ++it) {
            const int r = it * 8 + r0;
            *(ulonglong2*)&lA[r][sgm * 8] = *(const ulonglong2*)&Ab[(size_t)r * 256 + sgm * 8];
            *(ulonglong2*)&lB[r][sgm * 8] = *(const ulonglong2*)&Bbp[(size_t)r * 256 + sgm * 8];
        }
    }
    __syncthreads();

    const int r0 = (wave >> 1) * 64;   // row quadrant
    const int c0 = (wave & 1) * 64;    // col quadrant

    f32x4 acc[4][4];
#pragma unroll
    for (int ti = 0; ti < 4; ++ti)
#pragma unroll
        for (int tj = 0; tj < 4; ++tj) acc[ti][tj] = {0.f, 0.f, 0.f, 0.f};

#pragma unroll
    for (int kk = 0; kk < 8; ++kk) {
        s16x8 af[4], bf[4];
#pragma unroll
        for (int ti = 0; ti < 4; ++ti)
            af[ti] = *(const s16x8*)&lA[r0 + ti * 16 + lcol][kk * 32 + quad * 8];
#pragma unroll
        for (int tj = 0; tj < 4; ++tj)
            bf[tj] = *(const s16x8*)&lB[c0 + tj * 16 + lcol][kk * 32 + quad * 8];
#pragma unroll
        for (int ti = 0; ti < 4; ++ti)
#pragma unroll
            for (int tj = 0; tj < 4; ++tj)
                acc[ti][tj] = MF(af[ti], bf[tj], acc[ti][tj]);
    }

    // bias for this lane's 4 col-tiles
    float bias[4];
#pragma unroll
    for (int tj = 0; tj < 4; ++tj)
        bias[tj] = bcat[nt * 128 + c0 + tj * 16 + lcol];

    __syncthreads();   // all lA reads done; reuse lA as transposed staging

    unsigned short* lT = &lA[0][0];    // layout [col 0..127][132 row slots]
#pragma unroll
    for (int ti = 0; ti < 4; ++ti)
#pragma unroll
        for (int tj = 0; tj < 4; ++tj) {
            ushort4 v;
            v.x = f2bf(acc[ti][tj][0] + bias[tj]);
            v.y = f2bf(acc[ti][tj][1] + bias[tj]);
            v.z = f2bf(acc[ti][tj][2] + bias[tj]);
            v.w = f2bf(acc[ti][tj][3] + bias[tj]);
            const int colL = c0 + tj * 16 + lcol;
            const int rowL = r0 + ti * 16 + 4 * quad;
            *(ushort4*)&lT[(size_t)colL * 132 + rowL] = v;
        }
    __syncthreads();

    // write out: gx[((t*2+dir)*32 + chunkG)*384 + gc]*16 + i, coalesced ushort4
    const int dir = nt / 3;
    const int gcb = (nt % 3) * 128;
    const int bbC = bb >> 4;
    unsigned short* ob = gx + (((size_t)t * 2 + dir) * 32) * 384 * 16;
    const int k4 = tid & 3;
    const int g0 = (tid >> 2) & 63;
#pragma unroll
    for (int j = 0; j < 16; ++j) {
        const int chunk = j & 7, half = j >> 3;
        const int gcL = g0 + 64 * half;
        const ushort4 v = *(const ushort4*)&lT[(size_t)gcL * 132 + chunk * 16 + 4 * k4];
        *(ushort4*)&ob[(((size_t)(bbC + chunk)) * 384 + gcb + gcL) * 16 + 4 * k4] = v;
    }
}

// ---------------------------------------------------------------------------
// Layer 1 scan with hoisted Gx. grid = 64 (dir*32+chunk), block = 512 (8 waves).
// Wave w owns gate-cols [16w,16w+16) for r,z,n. ~110 VGPRs -> no spill.
// ---------------------------------------------------------------------------
__global__ __launch_bounds__(THREADS, 1) __attribute__((amdgpu_waves_per_eu(1, 2)))
void gru_l1h(
    const unsigned short* __restrict__ gx,
    const float* __restrict__ whh_f, const float* __restrict__ bhh_f,
    const float* __restrict__ whh_b, const float* __restrict__ bhh_b,
    float* __restrict__ finals)
{
    const int tid  = threadIdx.x;
    const int wave = tid >> 6;
    const int lane = tid & 63;
    const int lcol = lane & 15;
    const int quad = lane >> 4;
    const int dir   = blockIdx.x >> 5;
    const int chunk = blockIdx.x & 31;
    const int b0    = chunk * 16;
    const int c     = 16 * wave + lcol;

    const float* whh = dir ? whh_b : whh_f;
    const float* bhh = dir ? bhh_b : bhh_f;

    __shared__ __align__(16) unsigned short lds_h[2][16][136];

    const float bhr = bhh[c];
    const float bhz = bhh[128 + c];
    const float bhn = bhh[256 + c];

    s16x8 bh[3][4];
#pragma unroll
    for (int p = 0; p < 3; ++p) {
        const int nrow = p * 128 + c;
#pragma unroll
        for (int kk = 0; kk < 4; ++kk) {
            const float* src = &whh[(size_t)nrow * 128 + kk * 32 + quad * 8];
            s16x8 f;
#pragma unroll
            for (int j = 0; j < 8; ++j) f[j] = (short)f2bf(src[j]);
            bh[p][kk] = f;
        }
    }

    // Gx prefetch: lane needs (rows 4q..4q+3) x (3 gates) at col c for step s.
    auto loadGX = [&](ushort4 (&G)[3], int s) {
        const int t = dir ? (511 - s) : s;
        const unsigned short* gb =
            gx + ((((size_t)t * 2 + dir) * 32 + chunk) * 384) * 16;
#pragma unroll
        for (int g = 0; g < 3; ++g)
            G[g] = *(const ushort4*)&gb[(size_t)(g * 128 + c) * 16 + 4 * quad];
    };
    ushort4 G0[3], G1[3];
    loadGX(G0, 0);
    loadGX(G1, 1);

    float hreg[4] = {0.f, 0.f, 0.f, 0.f};
    for (int idx = tid; idx < 2 * 16 * 136; idx += THREADS)
        ((unsigned short*)lds_h)[idx] = 0;
    __syncthreads();

#define L1H_STEP(S, PAR, G)                                                    \
    do {                                                                       \
        const s16x8 a0 = *(const s16x8*)&lds_h[PAR][lcol][0  + quad * 8];      \
        const s16x8 a1 = *(const s16x8*)&lds_h[PAR][lcol][32 + quad * 8];      \
        const s16x8 a2 = *(const s16x8*)&lds_h[PAR][lcol][64 + quad * 8];      \
        const s16x8 a3 = *(const s16x8*)&lds_h[PAR][lcol][96 + quad * 8];      \
        f32x4 rA = {bhr, bhr, bhr, bhr}, rB = {0.f, 0.f, 0.f, 0.f};            \
        f32x4 zA = {bhz, bhz, bhz, bhz}, zB = {0.f, 0.f, 0.f, 0.f};            \
        f32x4 nA = {bhn, bhn, bhn, bhn}, nB = {0.f, 0.f, 0.f, 0.f};            \
        rA = MF(a0, bh[0][0], rA); zA = MF(a0, bh[1][0], zA);                  \
        nA = MF(a0, bh[2][0], nA);                                             \
        rB = MF(a1, bh[0][1], rB); zB = MF(a1, bh[1][1], zB);                  \
        nB = MF(a1, bh[2][1], nB);                                             \
        rA = MF(a2, bh[0][2], rA); zA = MF(a2, bh[1][2], zA);                  \
        nA = MF(a2, bh[2][2], nA);                                             \
        rB = MF(a3, bh[0][3], rB); zB = MF(a3, bh[1][3], zB);                  \
        nB = MF(a3, bh[2][3], nB);                                             \
        const unsigned short* gu = (const unsigned short*)&G[0];               \
        _Pragma("unroll")                                                      \
        for (int i = 0; i < 4; ++i) {                                          \
            const float gr = bf2f(((const unsigned short*)&G[0])[i]);          \
            const float gz = bf2f(((const unsigned short*)&G[1])[i]);          \
            const float gn = bf2f(((const unsigned short*)&G[2])[i]);          \
            const float r = fsig(rA[i] + rB[i] + gr);                          \
            const float z = fsig(zA[i] + zB[i] + gz);                          \
            const float n = ftanh(gn + r * (nA[i] + nB[i]));                   \
            hreg[i] = (1.0f - z) * n + z * hreg[i];                            \
            lds_h[PAR ^ 1][4 * quad + i][c] = f2bf(hreg[i]);                   \
        }                                                                      \
        (void)gu;                                                              \
        if ((S) < 510) {                                                       \
            loadGX(G, (S) + 2);                                                \
        } else if ((S) == 511) {                                               \
            _Pragma("unroll")                                                  \
            for (int i = 0; i < 4; ++i)                                        \
                finals[(size_t)(b0 + 4 * quad + i) * 256 + dir * 128 + c] =    \
                    hreg[i];                                                   \
        }                                                                      \
        WG_BARRIER();                                                          \
    } while (0)

    for (int s = 0; s < Tt; s += 2) {
        L1H_STEP(s,     0, G0);
        L1H_STEP(s + 1, 1, G1);
    }
#undef L1H_STEP
}

// ---------------------------------------------------------------------------
// Fallback layer-1 (fused Gx), R3 version — used only if ws too small.
// ---------------------------------------------------------------------------
__global__ __launch_bounds__(THREADS, 1) void gru_l1(
    const unsigned short* __restrict__ y0,
    const float* __restrict__ wih_f, const float* __restrict__ whh_f,
    const float* __restrict__ bih_f, const float* __restrict__ bhh_f,
    const float* __restrict__ wih_b, const float* __restrict__ whh_b,
    const float* __restrict__ bih_b, const float* __restrict__ bhh_b,
    float* __restrict__ finals)
{
    const int tid  = threadIdx.x;
    const int wave = tid >> 6;
    const int lane = tid & 63;
    const int lcol = lane & 15;
    const int quad = lane >> 4;
    const int dir   = blockIdx.x >> 5;
    const int b0    = (blockIdx.x & 31) * 16;
    const int c     = 16 * wave + lcol;

    const float* wih = dir ? wih_b : wih_f;
    const float* whh = dir ? whh_b : whh_f;
    const float* bih = dir ? bih_b : bih_f;
    const float* bhh = dir ? bhh_b : bhh_f;

    __shared__ __align__(16) unsigned short lds_h[2][16][136];

    const float br  = bih[c]       + bhh[c];
    const float bz  = bih[128 + c] + bhh[128 + c];
    const float bnx = bih[256 + c];
    const float bnh = bhh[256 + c];

    s16x8 bh[3][4];
    s16x8 bx[3][8];
#pragma unroll
    for (int p = 0; p < 3; ++p) {
        const int nrow = p * 128 + c;
#pragma unroll
        for (int kk = 0; kk < 4; ++kk) {
            const float* src = &whh[(size_t)nrow * 128 + kk * 32 + quad * 8];
            s16x8 f;
#pragma unroll
            for (int j = 0; j < 8; ++j) f[j] = (short)f2bf(src[j]);
            bh[p][kk] = f;
        }
#pragma unroll
        for (int kk = 0; kk < 8; ++kk) {
            const float* src = &wih[(size_t)nrow * 256 + kk * 32 + quad * 8];
            s16x8 f;
#pragma unroll
            for (int j = 0; j < 8; ++j) f[j] = (short)f2bf(src[j]);
            bx[p][kk] = f;
        }
    }

    auto loadP = [&](s16x8 (&P)[8], int t) {
        const unsigned short* pb = y0 + ((size_t)t * Bb + b0 + lcol) * 256 + quad * 8;
#pragma unroll
        for (int kk = 0; kk < 8; ++kk) P[kk] = *(const s16x8*)(pb + kk * 32);
    };
    s16x8 P0[8], P1[8];
    loadP(P0, dir ? 511 : 0);
    loadP(P1, dir ? 510 : 1);

    f32x4 accr = {br, br, br, br};
    f32x4 accz = {bz, bz, bz, bz};
    f32x4 accnx = {bnx, bnx, bnx, bnx};
#pragma unroll
    for (int kk = 0; kk < 8; ++kk) {
        accr  = MF(P0[kk], bx[0][kk], accr);
        accz  = MF(P0[kk], bx[1][kk], accz);
        accnx = MF(P0[kk], bx[2][kk], accnx);
    }
    loadP(P0, dir ? 509 : 2);

    float hreg[4] = {0.f, 0.f, 0.f, 0.f};
    for (int idx = tid; idx < 2 * 16 * 136; idx += THREADS)
        ((unsigned short*)lds_h)[idx] = 0;
    __syncthreads();

#define L1_STEP(S, PAR, PN)                                                    \
    do {                                                                       \
        const s16x8 a0 = *(const s16x8*)&lds_h[PAR][lcol][0  + quad * 8];      \
        const s16x8 a1 = *(const s16x8*)&lds_h[PAR][lcol][32 + quad * 8];      \
        const s16x8 a2 = *(const s16x8*)&lds_h[PAR][lcol][64 + quad * 8];      \
        const s16x8 a3 = *(const s16x8*)&lds_h[PAR][lcol][96 + quad * 8];      \
        f32x4 acchn = {bnh, bnh, bnh, bnh};                                    \
        accr = MF(a0, bh[0][0], accr); accz = MF(a0, bh[1][0], accz);          \
        acchn = MF(a0, bh[2][0], acchn);                                       \
        accr = MF(a1, bh[0][1], accr); accz = MF(a1, bh[1][1], accz);          \
        acchn = MF(a1, bh[2][1], acchn);                                       \
        accr = MF(a2, bh[0][2], accr); accz = MF(a2, bh[1][2], accz);          \
        acchn = MF(a2, bh[2][2], acchn);                                       \
        accr = MF(a3, bh[0][3], accr); accz = MF(a3, bh[1][3], accz);          \
        acchn = MF(a3, bh[2][3], acchn);                                       \
        _Pragma("unroll")                                                      \
        for (int i = 0; i < 4; ++i) {                                          \
            const float r = fsig(accr[i]);                                     \
            const float z = fsig(accz[i]);                                     \
            const float n = ftanh(accnx[i] + r * acchn[i]);                    \
            hreg[i] = (1.0f - z) * n + z * hreg[i];                            \
            lds_h[PAR ^ 1][4 * quad + i][c] = f2bf(hreg[i]);                   \
        }                                                                      \
        if ((S) < 511) {                                                       \
            accr = {br, br, br, br}; accz = {bz, bz, bz, bz};                  \
            accnx = {bnx, bnx, bnx, bnx};                                      \
            _Pragma("unroll")                                                  \
            for (int kk = 0; kk < 8; ++kk) {                                   \
                accr  = MF(PN[kk], bx[0][kk], accr);                           \
                accz  = MF(PN[kk], bx[1][kk], accz);                           \
                accnx = MF(PN[kk], bx[2][kk], accnx);                          \
            }                                                                  \
            int sp = (S) + 3; if (sp > 511) sp = 511;                          \
            loadP(PN, dir ? (511 - sp) : sp);                                  \
        } else {                                                               \
            _Pragma("unroll")                                                  \
            for (int i = 0; i < 4; ++i)                                        \
                finals[(size_t)(b0 + 4 * quad + i) * 256 + dir * 128 + c] =    \
                    hreg[i];                                                   \
        }                                                                      \
        WG_BARRIER();                                                          \
    } while (0)

    for (int s = 0; s < Tt; s += 2) {
        L1_STEP(s,     0, P1);
        L1_STEP(s + 1, 1, P0);
    }
#undef L1_STEP
}

// ---------------------------------------------------------------------------
// Layer 0 scan (unchanged from R3): K=4 scalar x-projection + MFMA Gh.
// ---------------------------------------------------------------------------
__global__ __launch_bounds__(THREADS, 1) __attribute__((amdgpu_waves_per_eu(1, 2)))
void gru_l0(
    const float* __restrict__ x,
    const float* __restrict__ wih_f, const float* __restrict__ whh_f,
    const float* __restrict__ bih_f, const float* __restrict__ bhh_f,
    const float* __restrict__ wih_b, const float* __restrict__ whh_b,
    const float* __restrict__ bih_b, const float* __restrict__ bhh_b,
    unsigned short* __restrict__ y0)
{
    const int tid  = threadIdx.x;
    const int wave = tid >> 6;
    const int lane = tid & 63;
    const int lcol = lane & 15;
    const int quad = lane >> 4;
    const int dir   = blockIdx.x >> 5;
    const int b0    = (blockIdx.x & 31) * 16;
    const int c     = 16 * wave + lcol;

    const float* wih = dir ? wih_b : wih_f;
    const float* whh = dir ? whh_b : whh_f;
    const float* bih = dir ? bih_b : bih_f;
    const float* bhh = dir ? bhh_b : bhh_f;

    __shared__ __align__(16) unsigned short lds_h[2][16][136];

    const float brs  = bih[c]       + bhh[c];
    const float bzs  = bih[128 + c] + bhh[128 + c];
    const float bnxs = bih[256 + c];
    const float bnh  = bhh[256 + c];

    float wr[4], wz[4], wn[4];
#pragma unroll
    for (int f = 0; f < 4; ++f) {
        wr[f] = wih[(c)       * 4 + f];
        wz[f] = wih[(128 + c) * 4 + f];
        wn[f] = wih[(256 + c) * 4 + f];
    }

    s16x8 bh[3][4];
#pragma unroll
    for (int p = 0; p < 3; ++p) {
        const int nrow = p * 128 + c;
#pragma unroll
        for (int kk = 0; kk < 4; ++kk) {
            const float* src = &whh[(size_t)nrow * 128 + kk * 32 + quad * 8];
            s16x8 f;
#pragma unroll
            for (int j = 0; j < 8; ++j) f[j] = (short)f2bf(src[j]);
            bh[p][kk] = f;
        }
    }

    auto loadX = [&](float4 (&X)[4], int t) {
#pragma unroll
        for (int i = 0; i < 4; ++i)
            X[i] = *(const float4*)&x[((size_t)(b0 + 4 * quad + i) * Tt + t) * 4];
    };
    float4 X0[4], X1[4];
    loadX(X0, dir ? 511 : 0);
    loadX(X1, dir ? 510 : 1);

    float xpr[4], xpz[4], xpn[4];
#pragma unroll
    for (int i = 0; i < 4; ++i) {
        xpr[i] = brs  + X0[i].x * wr[0] + X0[i].y * wr[1] + X0[i].z * wr[2] + X0[i].w * wr[3];
        xpz[i] = bzs  + X0[i].x * wz[0] + X0[i].y * wz[1] + X0[i].z * wz[2] + X0[i].w * wz[3];
        xpn[i] = bnxs + X0[i].x * wn[0] + X0[i].y * wn[1] + X0[i].z * wn[2] + X0[i].w * wn[3];
    }
    loadX(X0, dir ? 509 : 2);

    float hreg[4] = {0.f, 0.f, 0.f, 0.f};
    for (int idx = tid; idx < 2 * 16 * 136; idx += THREADS)
        ((unsigned short*)lds_h)[idx] = 0;
    __syncthreads();

    const int orow = tid >> 5;
    const int oc4  = (tid & 31) * 4;

#define L0_STEP(S, PAR, XN)                                                    \
    do {                                                                       \
        const int t = dir ? (511 - (S)) : (S);                                 \
        const s16x8 a0 = *(const s16x8*)&lds_h[PAR][lcol][0  + quad * 8];      \
        const s16x8 a1 = *(const s16x8*)&lds_h[PAR][lcol][32 + quad * 8];      \
        const s16x8 a2 = *(const s16x8*)&lds_h[PAR][lcol][64 + quad * 8];      \
        const s16x8 a3 = *(const s16x8*)&lds_h[PAR][lcol][96 + quad * 8];      \
        f32x4 accr  = {xpr[0], xpr[1], xpr[2], xpr[3]};                        \
        f32x4 accz  = {xpz[0], xpz[1], xpz[2], xpz[3]};                        \
        f32x4 acchn = {bnh, bnh, bnh, bnh};                                    \
        accr = MF(a0, bh[0][0], accr); accz = MF(a0, bh[1][0], accz);          \
        acchn = MF(a0, bh[2][0], acchn);                                       \
        accr = MF(a1, bh[0][1], accr); accz = MF(a1, bh[1][1], accz);          \
        acchn = MF(a1, bh[2][1], acchn);                                       \
        accr = MF(a2, bh[0][2], accr); accz = MF(a2, bh[1][2], accz);          \
        acchn = MF(a2, bh[2][2], acchn);                                       \
        accr = MF(a3, bh[0][3], accr); accz = MF(a3, bh[1][3], accz);          \
        acchn = MF(a3, bh[2][3], acchn);                                       \
        _Pragma("unroll")                                                      \
        for (int i = 0; i < 4; ++i) {                                          \
            const float r = fsig(accr[i]);                                     \
            const float z = fsig(accz[i]);                                     \
            const float n = ftanh(xpn[i] + r * acchn[i]);                      \
            hreg[i] = (1.0f - z) * n + z * hreg[i];                            \
            lds_h[PAR ^ 1][4 * quad + i][c] = f2bf(hreg[i]);                   \
        }                                                                      \
        if ((S) < 511) {                                                       \
            _Pragma("unroll")                                                  \
            for (int i = 0; i < 4; ++i) {                                      \
                xpr[i] = brs  + XN[i].x * wr[0] + XN[i].y * wr[1]              \
                              + XN[i].z * wr[2] + XN[i].w * wr[3];             \
                xpz[i] = bzs  + XN[i].x * wz[0] + XN[i].y * wz[1]              \
                              + XN[i].z * wz[2] + XN[i].w * wz[3];             \
                xpn[i] = bnxs + XN[i].x * wn[0] + XN[i].y * wn[1]              \
                              + XN[i].z * wn[2] + XN[i].w * wn[3];             \
            }                                                                  \
            int sp = (S) + 3; if (sp > 511) sp = 511;                          \
            loadX(XN, dir ? (511 - sp) : sp);                                  \
        }                                                                      \
        WG_BARRIER();                                                          \
        {                                                                      \
            const ushort4 hv4 = *(const ushort4*)&lds_h[PAR ^ 1][orow][oc4];   \
            *(ushort4*)&y0[((size_t)t * Bb + b0 + orow) * 256 + dir * 128 +    \
                           oc4] = hv4;                                         \
        }                                                                      \
    } while (0)

    for (int s = 0; s < Tt; s += 2) {
        L0_STEP(s,     0, X1);
        L0_STEP(s + 1, 1, X0);
    }
#undef L0_STEP
}

// ---------------------------------------------------------------------------
// FC head
// ---------------------------------------------------------------------------
__global__ __launch_bounds__(128) void fc_head(
    const float* __restrict__ finals,
    const float* __restrict__ fc1w, const float* __restrict__ fc1b,
    const float* __restrict__ fc2w, const float* __restrict__ fc2b,
    float* __restrict__ out)
{
    __shared__ float s_in[256];
    __shared__ float s_h1[128];
    const int b = blockIdx.x, tid = threadIdx.x;
    s_in[tid]       = finals[(size_t)b * 256 + tid];
    s_in[tid + 128] = finals[(size_t)b * 256 + 128 + tid];
    __syncthreads();
    float acc = fc1b[tid];
    const float* wrow = &fc1w[tid * 256];
#pragma unroll 8
    for (int i = 0; i < 256; ++i) acc += s_in[i] * wrow[i];
    s_h1[tid] = fmaxf(acc, 0.0f);
    __syncthreads();
    if (tid < 2) {
        float a = fc2b[tid];
        const float* w2 = &fc2w[tid * 128];
#pragma unroll 8
        for (int i = 0; i < 128; ++i) a += s_h1[i] * w2[i];
        out[b * 2 + tid] = a;
    }
}

extern "C" void kernel_launch(void* const* d_in, const int* in_sizes, int n_in,
                              void* d_out, int out_size, void* d_ws, size_t ws_size,
                              hipStream_t stream) {
    const float* x      = (const float*)d_in[0];
    const float* wih0f  = (const float*)d_in[1];
    const float* whh0f  = (const float*)d_in[2];
    const float* bih0f  = (const float*)d_in[3];
    const float* bhh0f  = (const float*)d_in[4];
    const float* wih0b  = (const float*)d_in[5];
    const float* whh0b  = (const float*)d_in[6];
    const float* bih0b  = (const float*)d_in[7];
    const float* bhh0b  = (const float*)d_in[8];
    const float* wih1f  = (const float*)d_in[9];
    const float* whh1f  = (const float*)d_in[10];
    const float* bih1f  = (const float*)d_in[11];
    const float* bhh1f  = (const float*)d_in[12];
    const float* wih1b  = (const float*)d_in[13];
    const float* whh1b  = (const float*)d_in[14];
    const float* bih1b  = (const float*)d_in[15];
    const float* bhh1b  = (const float*)d_in[16];
    const float* fc1w   = (const float*)d_in[17];
    const float* fc1b   = (const float*)d_in[18];
    const float* fc2w   = (const float*)d_in[19];
    const float* fc2b   = (const float*)d_in[20];

    const size_t Y0SZ = 134217728ull;   // y0 bf16 [512][512][256]
    const size_t GXSZ = 402653184ull;   // gx bf16 [512][2][32][384][16]
    const size_t WCSZ = 393216ull;      // wcat bf16 [768][256]
    const size_t BCSZ = 3072ull;        // bcat f32 [768]
    const size_t FISZ = 524288ull;      // finals f32 [512][256]

    unsigned short* y0 = (unsigned short*)d_ws;
    float* out = (float*)d_out;

    if (ws_size >= Y0SZ + GXSZ + WCSZ + BCSZ + FISZ) {
        unsigned short* gxp  = (unsigned short*)((char*)d_ws + Y0SZ);
        unsigned short* wcat = (unsigned short*)((char*)d_ws + Y0SZ + GXSZ);
        float* bcat   = (float*)((char*)d_ws + Y0SZ + GXSZ + WCSZ);
        float* finals = (float*)((char*)d_ws + Y0SZ + GXSZ + WCSZ + BCSZ);

        w_prep<<<dim3(768), dim3(256), 0, stream>>>(wih1f, wih1b, bih1f, bih1b, wcat, bcat);
        gru_l0<<<dim3(64), dim3(THREADS), 0, stream>>>(
            x, wih0f, whh0f, bih0f, bhh0f, wih0b, whh0b, bih0b, bhh0b, y0);
        gx_gemm<<<dim3(12288), dim3(256), 0, stream>>>(y0, wcat, bcat, gxp);
        gru_l1h<<<dim3(64), dim3(THREADS), 0, stream>>>(
            gxp, whh1f, bhh1f, whh1b, bhh1b, finals);
        fc_head<<<dim3(Bb), dim3(128), 0, stream>>>(finals, fc1w, fc1b, fc2w, fc2b, out);
    } else {
        float* finals = (float*)((char*)d_ws + Y0SZ);
        gru_l0<<<dim3(64), dim3(THREADS), 0, stream>>>(
            x, wih0f, whh0f, bih0f, bhh0f, wih0b, whh0b, bih0b, bhh0b, y0);
        gru_l1<<<dim3(64), dim3(THREADS), 0, stream>>>(
            y0, wih1f, whh1f, bih1f, bhh1f, wih1b, whh1b, bih1b, bhh1b, finals);
        fc_head<<<dim3(Bb), dim3(128), 0, stream>>>(finals, fc1w, fc1b, fc2w, fc2b, out);
    }
}

// Round 7
// 1328.670 us; speedup vs baseline: 1.6062x; 1.6062x over previous
//
#include <hip/hip_runtime.h>
#include <stdint.h>

// GRUClassifier: 2-layer bidir GRU (H=128, T=512, B=512) + FC head.
// R7: fix gx_gemm LDS overflow (R4-R6 staged a 128x256 K-panel into a
// 128x136 buffer -> row aliasing + out-of-bounds). K now processed in two
// 128-wide halves; per-half staging fits lA/lB[128][136] exactly.
// Everything else verbatim from R6 (audited): chunked hoisted Gx, natural
// gxc layout [slot][b][gc] bf16, light scan kernel with only W_hh resident.

#define Tt 512
#define Bb 512
#define THREADS 512

using s16x8 = __attribute__((ext_vector_type(8))) short;  // 8 bf16 (4 VGPRs)
using f32x4 = __attribute__((ext_vector_type(4))) float;

#define MF(a, b, c) __builtin_amdgcn_mfma_f32_16x16x32_bf16((a), (b), (c), 0, 0, 0)

__device__ __forceinline__ unsigned short f2bf(float f) {
    union { float f; unsigned int u; } v; v.f = f;
    unsigned int u = v.u;
    u += 0x7fffu + ((u >> 16) & 1u);   // RNE
    return (unsigned short)(u >> 16);
}
__device__ __forceinline__ float bf2f(unsigned short h) {
    union { unsigned int u; float f; } v; v.u = ((unsigned int)h) << 16;
    return v.f;
}

__device__ __forceinline__ float fsig(float x) {
    return __builtin_amdgcn_rcpf(1.0f + __expf(-x));
}
__device__ __forceinline__ float ftanh(float x) {
    return 2.0f * __builtin_amdgcn_rcpf(1.0f + __expf(-2.0f * x)) - 1.0f;
}

// Raw workgroup barrier: drains LDS ops only; in-flight global register
// prefetch loads survive it (vmcnt not drained).
#define WG_BARRIER() asm volatile("s_waitcnt lgkmcnt(0)\n\ts_barrier" ::: "memory")

// ---------------------------------------------------------------------------
// w_prep: pack W_ih1 (both dirs) to bf16 [768][256] + bias concat [768].
// ---------------------------------------------------------------------------
__global__ void w_prep(const float* __restrict__ wihf, const float* __restrict__ wihb,
                       const float* __restrict__ bihf, const float* __restrict__ bihb,
                       unsigned short* __restrict__ wcat, float* __restrict__ bcat)
{
    const int n = blockIdx.x;   // 0..767
    const int k = threadIdx.x;  // 0..255
    const float* src = (n < 384) ? &wihf[(size_t)n * 256] : &wihb[(size_t)(n - 384) * 256];
    wcat[(size_t)n * 256 + k] = f2bf(src[k]);
    if (k == 0) bcat[n] = (n < 384) ? bihf[n] : bihb[n - 384];
}

// ---------------------------------------------------------------------------
// gx_gemm: Gx tile for one (slot, batch-tile, n-tile). slot = dir*CT + sl;
// fwd t = kc*CT+sl, bwd t = 511-(kc*CT+sl). Output bf16, natural layout:
//   gxc[(dir*CT + sl)*512*384 + b*384 + gc],  gc = gate*128 + col.
// K=256 processed in TWO 128-wide halves (LDS tiles are 128x128; R6's
// single-shot staging overflowed the buffers). grid = 24*CT, block = 256.
// ---------------------------------------------------------------------------
__global__ __launch_bounds__(256) void gx_gemm(
    const unsigned short* __restrict__ y0,
    const unsigned short* __restrict__ wcat,
    const float* __restrict__ bcat,
    unsigned short* __restrict__ gxc,
    int kc, int CT)
{
    int bx = blockIdx.x;
    const int nt  = bx % 3;  bx /= 3;    // n-tile (128 gate cols)
    const int bt  = bx & 3;  bx >>= 2;   // batch tile (128 rows)
    const int sl  = bx % CT;             // local step
    const int dir = bx / CT;
    const int s   = kc * CT + sl;
    const int t   = dir ? (511 - s) : s;
    const int bb  = bt << 7;

    const int tid  = threadIdx.x;
    const int wave = tid >> 6;
    const int lane = tid & 63;
    const int lcol = lane & 15;
    const int quad = lane >> 4;

    __shared__ __align__(16) unsigned short lA[128][136];
    __shared__ __align__(16) unsigned short lB[128][136];

    const unsigned short* Abase = y0 + ((size_t)t * 512 + bb) * 256;
    const unsigned short* Bbase = wcat + ((size_t)dir * 384 + nt * 128) * 256;

    const int r0 = (wave >> 1) * 64;   // row quadrant (batch)
    const int c0 = (wave & 1) * 64;    // col quadrant (gate col)

    f32x4 acc[4][4];
#pragma unroll
    for (int ti = 0; ti < 4; ++ti)
#pragma unroll
        for (int tj = 0; tj < 4; ++tj) acc[ti][tj] = {0.f, 0.f, 0.f, 0.f};

    const int r0s = tid >> 4;          // 0..15
    const int sgm = (tid & 15) * 8;    // 0..120  (in-bounds: <136)

#pragma unroll
    for (int kh = 0; kh < 2; ++kh) {
        if (kh) __syncthreads();       // protect restage from prior reads
        // stage 128x128 half: A rows (batch), B rows (gate cols)
#pragma unroll
        for (int it = 0; it < 8; ++it) {
            const int r = it * 16 + r0s;
            *(ulonglong2*)&lA[r][sgm] =
                *(const ulonglong2*)&Abase[(size_t)r * 256 + kh * 128 + sgm];
            *(ulonglong2*)&lB[r][sgm] =
                *(const ulonglong2*)&Bbase[(size_t)r * 256 + kh * 128 + sgm];
        }
        __syncthreads();

#pragma unroll
        for (int kk = 0; kk < 4; ++kk) {
            s16x8 af[4], bfv[4];
#pragma unroll
            for (int ti = 0; ti < 4; ++ti)
                af[ti] = *(const s16x8*)&lA[r0 + ti * 16 + lcol][kk * 32 + quad * 8];
#pragma unroll
            for (int tj = 0; tj < 4; ++tj)
                bfv[tj] = *(const s16x8*)&lB[c0 + tj * 16 + lcol][kk * 32 + quad * 8];
#pragma unroll
            for (int ti = 0; ti < 4; ++ti)
#pragma unroll
                for (int tj = 0; tj < 4; ++tj)
                    acc[ti][tj] = MF(af[ti], bfv[tj], acc[ti][tj]);
        }
    }

    float bias[4];
#pragma unroll
    for (int tj = 0; tj < 4; ++tj)
        bias[tj] = bcat[dir * 384 + nt * 128 + c0 + tj * 16 + lcol];

    __syncthreads();   // all fragment reads done; reuse lA as C staging

    // stage C row-major: lC[row][col], row stride 136, cols 0..127 (in-bounds)
    unsigned short* lC = &lA[0][0];
#pragma unroll
    for (int ti = 0; ti < 4; ++ti)
#pragma unroll
        for (int tj = 0; tj < 4; ++tj) {
            const int col = c0 + tj * 16 + lcol;
#pragma unroll
            for (int i = 0; i < 4; ++i)
                lC[(size_t)(r0 + ti * 16 + 4 * quad + i) * 136 + col] =
                    f2bf(acc[ti][tj][i] + bias[tj]);
        }
    __syncthreads();

    // coalesced contiguous row writes: row r -> gxc[slot][bb+r][nt*128 .. +128]
    unsigned short* ob = gxc + ((size_t)(dir * CT + sl) * 512 + bb) * 384 + nt * 128;
#pragma unroll
    for (int it = 0; it < 8; ++it) {
        const int r = it * 16 + r0s;
        *(ulonglong2*)&ob[(size_t)r * 384 + sgm] = *(const ulonglong2*)&lC[(size_t)r * 136 + sgm];
    }
}

// ---------------------------------------------------------------------------
// gru_l1c: CT steps of the layer-1 scan with hoisted Gx (bf16). h-state in ws
// (layout = finals: hstate[b*256 + dir*128 + c], fp32). ~100 VGPRs, no spill.
// grid = 64 (dir*32+chunk), block = 512 (8 waves).
// ---------------------------------------------------------------------------
__global__ __launch_bounds__(THREADS) void gru_l1c(
    const unsigned short* __restrict__ gxc,
    const float* __restrict__ whh_f, const float* __restrict__ bhh_f,
    const float* __restrict__ whh_b, const float* __restrict__ bhh_b,
    float* __restrict__ hstate,
    int CT, int first)
{
    const int tid  = threadIdx.x;
    const int wave = tid >> 6;
    const int lane = tid & 63;
    const int lcol = lane & 15;
    const int quad = lane >> 4;
    const int dir   = blockIdx.x >> 5;
    const int chunk = blockIdx.x & 31;
    const int b0    = chunk * 16;
    const int c     = 16 * wave + lcol;

    const float* whh = dir ? whh_b : whh_f;
    const float* bhh = dir ? bhh_b : bhh_f;

    __shared__ __align__(16) unsigned short lds_h[2][16][136];

    const float bhr = bhh[c];
    const float bhz = bhh[128 + c];
    const float bhn = bhh[256 + c];

    s16x8 bh[3][4];
#pragma unroll
    for (int p = 0; p < 3; ++p) {
        const int nrow = p * 128 + c;
#pragma unroll
        for (int kk = 0; kk < 4; ++kk) {
            const float* src = &whh[(size_t)nrow * 128 + kk * 32 + quad * 8];
            s16x8 f;
#pragma unroll
            for (int j = 0; j < 8; ++j) f[j] = (short)f2bf(src[j]);
            bh[p][kk] = f;
        }
    }

    // G layout: G[g*4+i] = gxc[(dir*CT+sl)*512*384 + (b0+4*quad+i)*384 + g*128+c]
    const unsigned short* gbase = gxc + (size_t)dir * CT * 512 * 384;
    auto loadGX = [&](unsigned short (&G)[12], int sl) {
        const unsigned short* gp = gbase + ((size_t)sl * 512 + b0 + 4 * quad) * 384;
#pragma unroll
        for (int g = 0; g < 3; ++g)
#pragma unroll
            for (int i = 0; i < 4; ++i)
                G[g * 4 + i] = gp[(size_t)i * 384 + g * 128 + c];
    };
    unsigned short G0[12], G1[12];
    loadGX(G0, 0);
    loadGX(G1, 1);

    // h init: zeros on first chunk, else persisted state.
    float hreg[4];
    const int gb2 = tid >> 5;          // 0..15 batch row for LDS init
    const int j0  = (tid & 31) * 4;    // 0..124
    if (first) {
#pragma unroll
        for (int i = 0; i < 4; ++i) hreg[i] = 0.f;
        ushort4 z4; z4.x = 0; z4.y = 0; z4.z = 0; z4.w = 0;
        *(ushort4*)&lds_h[0][gb2][j0] = z4;
    } else {
#pragma unroll
        for (int i = 0; i < 4; ++i)
            hreg[i] = hstate[(size_t)(b0 + 4 * quad + i) * 256 + dir * 128 + c];
        ushort4 hv;
        hv.x = f2bf(hstate[(size_t)(b0 + gb2) * 256 + dir * 128 + j0 + 0]);
        hv.y = f2bf(hstate[(size_t)(b0 + gb2) * 256 + dir * 128 + j0 + 1]);
        hv.z = f2bf(hstate[(size_t)(b0 + gb2) * 256 + dir * 128 + j0 + 2]);
        hv.w = f2bf(hstate[(size_t)(b0 + gb2) * 256 + dir * 128 + j0 + 3]);
        *(ushort4*)&lds_h[0][gb2][j0] = hv;
    }
    __syncthreads();

#define L1C_STEP(S, PAR, G)                                                    \
    do {                                                                       \
        const s16x8 a0 = *(const s16x8*)&lds_h[PAR][lcol][0  + quad * 8];      \
        const s16x8 a1 = *(const s16x8*)&lds_h[PAR][lcol][32 + quad * 8];      \
        const s16x8 a2 = *(const s16x8*)&lds_h[PAR][lcol][64 + quad * 8];      \
        const s16x8 a3 = *(const s16x8*)&lds_h[PAR][lcol][96 + quad * 8];      \
        f32x4 rA = {bhr, bhr, bhr, bhr}, rB = {0.f, 0.f, 0.f, 0.f};            \
        f32x4 zA = {bhz, bhz, bhz, bhz}, zB = {0.f, 0.f, 0.f, 0.f};            \
        f32x4 nA = {bhn, bhn, bhn, bhn}, nB = {0.f, 0.f, 0.f, 0.f};            \
        rA = MF(a0, bh[0][0], rA); zA = MF(a0, bh[1][0], zA);                  \
        nA = MF(a0, bh[2][0], nA);                                             \
        rB = MF(a1, bh[0][1], rB); zB = MF(a1, bh[1][1], zB);                  \
        nB = MF(a1, bh[2][1], nB);                                             \
        rA = MF(a2, bh[0][2], rA); zA = MF(a2, bh[1][2], zA);                  \
        nA = MF(a2, bh[2][2], nA);                                             \
        rB = MF(a3, bh[0][3], rB); zB = MF(a3, bh[1][3], zB);                  \
        nB = MF(a3, bh[2][3], nB);                                             \
        _Pragma("unroll")                                                      \
        for (int i = 0; i < 4; ++i) {                                          \
            const float r = fsig(rA[i] + rB[i] + bf2f(G[i]));                  \
            const float z = fsig(zA[i] + zB[i] + bf2f(G[4 + i]));              \
            const float n = ftanh(bf2f(G[8 + i]) + r * (nA[i] + nB[i]));       \
            hreg[i] = (1.0f - z) * n + z * hreg[i];                            \
            lds_h[PAR ^ 1][4 * quad + i][c] = f2bf(hreg[i]);                   \
        }                                                                      \
        if ((S) < CT - 2) {                                                    \
            loadGX(G, (S) + 2);                                                \
        } else if ((S) == CT - 1) {                                            \
            _Pragma("unroll")                                                  \
            for (int i = 0; i < 4; ++i)                                        \
                hstate[(size_t)(b0 + 4 * quad + i) * 256 + dir * 128 + c] =    \
                    hreg[i];                                                   \
        }                                                                      \
        WG_BARRIER();                                                          \
    } while (0)

    for (int sl = 0; sl < CT; sl += 2) {
        L1C_STEP(sl,     0, G0);
        L1C_STEP(sl + 1, 1, G1);
    }
#undef L1C_STEP
}

// ---------------------------------------------------------------------------
// Fallback layer-1 (fused Gx, verbatim from passing R3) — if no CT fits.
// ---------------------------------------------------------------------------
__global__ __launch_bounds__(THREADS, 1) void gru_l1(
    const unsigned short* __restrict__ y0,
    const float* __restrict__ wih_f, const float* __restrict__ whh_f,
    const float* __restrict__ bih_f, const float* __restrict__ bhh_f,
    const float* __restrict__ wih_b, const float* __restrict__ whh_b,
    const float* __restrict__ bih_b, const float* __restrict__ bhh_b,
    float* __restrict__ finals)
{
    const int tid  = threadIdx.x;
    const int wave = tid >> 6;
    const int lane = tid & 63;
    const int lcol = lane & 15;
    const int quad = lane >> 4;
    const int dir   = blockIdx.x >> 5;
    const int b0    = (blockIdx.x & 31) * 16;
    const int c     = 16 * wave + lcol;

    const float* wih = dir ? wih_b : wih_f;
    const float* whh = dir ? whh_b : whh_f;
    const float* bih = dir ? bih_b : bih_f;
    const float* bhh = dir ? bhh_b : bhh_f;

    __shared__ __align__(16) unsigned short lds_h[2][16][136];

    const float br  = bih[c]       + bhh[c];
    const float bz  = bih[128 + c] + bhh[128 + c];
    const float bnx = bih[256 + c];
    const float bnh = bhh[256 + c];

    s16x8 bh[3][4];
    s16x8 bx[3][8];
#pragma unroll
    for (int p = 0; p < 3; ++p) {
        const int nrow = p * 128 + c;
#pragma unroll
        for (int kk = 0; kk < 4; ++kk) {
            const float* src = &whh[(size_t)nrow * 128 + kk * 32 + quad * 8];
            s16x8 f;
#pragma unroll
            for (int j = 0; j < 8; ++j) f[j] = (short)f2bf(src[j]);
            bh[p][kk] = f;
        }
#pragma unroll
        for (int kk = 0; kk < 8; ++kk) {
            const float* src = &wih[(size_t)nrow * 256 + kk * 32 + quad * 8];
            s16x8 f;
#pragma unroll
            for (int j = 0; j < 8; ++j) f[j] = (short)f2bf(src[j]);
            bx[p][kk] = f;
        }
    }

    auto loadP = [&](s16x8 (&P)[8], int t) {
        const unsigned short* pb = y0 + ((size_t)t * Bb + b0 + lcol) * 256 + quad * 8;
#pragma unroll
        for (int kk = 0; kk < 8; ++kk) P[kk] = *(const s16x8*)(pb + kk * 32);
    };
    s16x8 P0[8], P1[8];
    loadP(P0, dir ? 511 : 0);
    loadP(P1, dir ? 510 : 1);

    f32x4 accr = {br, br, br, br};
    f32x4 accz = {bz, bz, bz, bz};
    f32x4 accnx = {bnx, bnx, bnx, bnx};
#pragma unroll
    for (int kk = 0; kk < 8; ++kk) {
        accr  = MF(P0[kk], bx[0][kk], accr);
        accz  = MF(P0[kk], bx[1][kk], accz);
        accnx = MF(P0[kk], bx[2][kk], accnx);
    }
    loadP(P0, dir ? 509 : 2);

    float hreg[4] = {0.f, 0.f, 0.f, 0.f};
    for (int idx = tid; idx < 2 * 16 * 136; idx += THREADS)
        ((unsigned short*)lds_h)[idx] = 0;
    __syncthreads();

#define L1_STEP(S, PAR, PN)                                                    \
    do {                                                                       \
        const s16x8 a0 = *(const s16x8*)&lds_h[PAR][lcol][0  + quad * 8];      \
        const s16x8 a1 = *(const s16x8*)&lds_h[PAR][lcol][32 + quad * 8];      \
        const s16x8 a2 = *(const s16x8*)&lds_h[PAR][lcol][64 + quad * 8];      \
        const s16x8 a3 = *(const s16x8*)&lds_h[PAR][lcol][96 + quad * 8];      \
        f32x4 acchn = {bnh, bnh, bnh, bnh};                                    \
        accr = MF(a0, bh[0][0], accr); accz = MF(a0, bh[1][0], accz);          \
        acchn = MF(a0, bh[2][0], acchn);                                       \
        accr = MF(a1, bh[0][1], accr); accz = MF(a1, bh[1][1], accz);          \
        acchn = MF(a1, bh[2][1], acchn);                                       \
        accr = MF(a2, bh[0][2], accr); accz = MF(a2, bh[1][2], accz);          \
        acchn = MF(a2, bh[2][2], acchn);                                       \
        accr = MF(a3, bh[0][3], accr); accz = MF(a3, bh[1][3], accz);          \
        acchn = MF(a3, bh[2][3], acchn);                                       \
        _Pragma("unroll")                                                      \
        for (int i = 0; i < 4; ++i) {                                          \
            const float r = fsig(accr[i]);                                     \
            const float z = fsig(accz[i]);                                     \
            const float n = ftanh(accnx[i] + r * acchn[i]);                    \
            hreg[i] = (1.0f - z) * n + z * hreg[i];                            \
            lds_h[PAR ^ 1][4 * quad + i][c] = f2bf(hreg[i]);                   \
        }                                                                      \
        if ((S) < 511) {                                                       \
            accr = {br, br, br, br}; accz = {bz, bz, bz, bz};                  \
            accnx = {bnx, bnx, bnx, bnx};                                      \
            _Pragma("unroll")                                                  \
            for (int kk = 0; kk < 8; ++kk) {                                   \
                accr  = MF(PN[kk], bx[0][kk], accr);                           \
                accz  = MF(PN[kk], bx[1][kk], accz);                           \
                accnx = MF(PN[kk], bx[2][kk], accnx);                          \
            }                                                                  \
            int sp = (S) + 3; if (sp > 511) sp = 511;                          \
            loadP(PN, dir ? (511 - sp) : sp);                                  \
        } else {                                                               \
            _Pragma("unroll")                                                  \
            for (int i = 0; i < 4; ++i)                                        \
                finals[(size_t)(b0 + 4 * quad + i) * 256 + dir * 128 + c] =    \
                    hreg[i];                                                   \
        }                                                                      \
        WG_BARRIER();                                                          \
    } while (0)

    for (int s = 0; s < Tt; s += 2) {
        L1_STEP(s,     0, P1);
        L1_STEP(s + 1, 1, P0);
    }
#undef L1_STEP
}

// ---------------------------------------------------------------------------
// Layer 0 scan (verbatim from passing R3): K=4 scalar x-projection + MFMA Gh.
// ---------------------------------------------------------------------------
__global__ __launch_bounds__(THREADS, 1) void gru_l0(
    const float* __restrict__ x,
    const float* __restrict__ wih_f, const float* __restrict__ whh_f,
    const float* __restrict__ bih_f, const float* __restrict__ bhh_f,
    const float* __restrict__ wih_b, const float* __restrict__ whh_b,
    const float* __restrict__ bih_b, const float* __restrict__ bhh_b,
    unsigned short* __restrict__ y0)
{
    const int tid  = threadIdx.x;
    const int wave = tid >> 6;
    const int lane = tid & 63;
    const int lcol = lane & 15;
    const int quad = lane >> 4;
    const int dir   = blockIdx.x >> 5;
    const int b0    = (blockIdx.x & 31) * 16;
    const int c     = 16 * wave + lcol;

    const float* wih = dir ? wih_b : wih_f;
    const float* whh = dir ? whh_b : whh_f;
    const float* bih = dir ? bih_b : bih_f;
    const float* bhh = dir ? bhh_b : bhh_f;

    __shared__ __align__(16) unsigned short lds_h[2][16][136];

    const float brs  = bih[c]       + bhh[c];
    const float bzs  = bih[128 + c] + bhh[128 + c];
    const float bnxs = bih[256 + c];
    const float bnh  = bhh[256 + c];

    float wr[4], wz[4], wn[4];
#pragma unroll
    for (int f = 0; f < 4; ++f) {
        wr[f] = wih[(c)       * 4 + f];
        wz[f] = wih[(128 + c) * 4 + f];
        wn[f] = wih[(256 + c) * 4 + f];
    }

    s16x8 bh[3][4];
#pragma unroll
    for (int p = 0; p < 3; ++p) {
        const int nrow = p * 128 + c;
#pragma unroll
        for (int kk = 0; kk < 4; ++kk) {
            const float* src = &whh[(size_t)nrow * 128 + kk * 32 + quad * 8];
            s16x8 f;
#pragma unroll
            for (int j = 0; j < 8; ++j) f[j] = (short)f2bf(src[j]);
            bh[p][kk] = f;
        }
    }

    auto loadX = [&](float4 (&X)[4], int t) {
#pragma unroll
        for (int i = 0; i < 4; ++i)
            X[i] = *(const float4*)&x[((size_t)(b0 + 4 * quad + i) * Tt + t) * 4];
    };
    float4 X0[4], X1[4];
    loadX(X0, dir ? 511 : 0);
    loadX(X1, dir ? 510 : 1);

    float xpr[4], xpz[4], xpn[4];
#pragma unroll
    for (int i = 0; i < 4; ++i) {
        xpr[i] = brs  + X0[i].x * wr[0] + X0[i].y * wr[1] + X0[i].z * wr[2] + X0[i].w * wr[3];
        xpz[i] = bzs  + X0[i].x * wz[0] + X0[i].y * wz[1] + X0[i].z * wz[2] + X0[i].w * wz[3];
        xpn[i] = bnxs + X0[i].x * wn[0] + X0[i].y * wn[1] + X0[i].z * wn[2] + X0[i].w * wn[3];
    }
    loadX(X0, dir ? 509 : 2);

    float hreg[4] = {0.f, 0.f, 0.f, 0.f};
    for (int idx = tid; idx < 2 * 16 * 136; idx += THREADS)
        ((unsigned short*)lds_h)[idx] = 0;
    __syncthreads();

    const int orow = tid >> 5;
    const int oc4  = (tid & 31) * 4;

#define L0_STEP(S, PAR, XN)                                                    \
    do {                                                                       \
        const int t = dir ? (511 - (S)) : (S);                                 \
        const s16x8 a0 = *(const s16x8*)&lds_h[PAR][lcol][0  + quad * 8];      \
        const s16x8 a1 = *(const s16x8*)&lds_h[PAR][lcol][32 + quad * 8];      \
        const s16x8 a2 = *(const s16x8*)&lds_h[PAR][lcol][64 + quad * 8];      \
        const s16x8 a3 = *(const s16x8*)&lds_h[PAR][lcol][96 + quad * 8];      \
        f32x4 accr  = {xpr[0], xpr[1], xpr[2], xpr[3]};                        \
        f32x4 accz  = {xpz[0], xpz[1], xpz[2], xpz[3]};                        \
        f32x4 acchn = {bnh, bnh, bnh, bnh};                                    \
        accr = MF(a0, bh[0][0], accr); accz = MF(a0, bh[1][0], accz);          \
        acchn = MF(a0, bh[2][0], acchn);                                       \
        accr = MF(a1, bh[0][1], accr); accz = MF(a1, bh[1][1], accz);          \
        acchn = MF(a1, bh[2][1], acchn);                                       \
        accr = MF(a2, bh[0][2], accr); accz = MF(a2, bh[1][2], accz);          \
        acchn = MF(a2, bh[2][2], acchn);                                       \
        accr = MF(a3, bh[0][3], accr); accz = MF(a3, bh[1][3], accz);          \
        acchn = MF(a3, bh[2][3], acchn);                                       \
        _Pragma("unroll")                                                      \
        for (int i = 0; i < 4; ++i) {                                          \
            const float r = fsig(accr[i]);                                     \
            const float z = fsig(accz[i]);                                     \
            const float n = ftanh(xpn[i] + r * acchn[i]);                      \
            hreg[i] = (1.0f - z) * n + z * hreg[i];                            \
            lds_h[PAR ^ 1][4 * quad + i][c] = f2bf(hreg[i]);                   \
        }                                                                      \
        if ((S) < 511) {                                                       \
            _Pragma("unroll")                                                  \
            for (int i = 0; i < 4; ++i) {                                      \
                xpr[i] = brs  + XN[i].x * wr[0] + XN[i].y * wr[1]              \
                              + XN[i].z * wr[2] + XN[i].w * wr[3];             \
                xpz[i] = bzs  + XN[i].x * wz[0] + XN[i].y * wz[1]              \
                              + XN[i].z * wz[2] + XN[i].w * wz[3];             \
                xpn[i] = bnxs + XN[i].x * wn[0] + XN[i].y * wn[1]              \
                              + XN[i].z * wn[2] + XN[i].w * wn[3];             \
            }                                                                  \
            int sp = (S) + 3; if (sp > 511) sp = 511;                          \
            loadX(XN, dir ? (511 - sp) : sp);                                  \
        }                                                                      \
        WG_BARRIER();                                                          \
        {                                                                      \
            const ushort4 hv4 = *(const ushort4*)&lds_h[PAR ^ 1][orow][oc4];   \
            *(ushort4*)&y0[((size_t)t * Bb + b0 + orow) * 256 + dir * 128 +    \
                           oc4] = hv4;                                         \
        }                                                                      \
    } while (0)

    for (int s = 0; s < Tt; s += 2) {
        L0_STEP(s,     0, X1);
        L0_STEP(s + 1, 1, X0);
    }
#undef L0_STEP
}

// ---------------------------------------------------------------------------
// FC head: out = relu(finals @ fc1^T + b1) @ fc2^T + b2   [512,256]->[512,2]
// ---------------------------------------------------------------------------
__global__ __launch_bounds__(128) void fc_head(
    const float* __restrict__ finals,
    const float* __restrict__ fc1w, const float* __restrict__ fc1b,
    const float* __restrict__ fc2w, const float* __restrict__ fc2b,
    float* __restrict__ out)
{
    __shared__ float s_in[256];
    __shared__ float s_h1[128];
    const int b = blockIdx.x, tid = threadIdx.x;
    s_in[tid]       = finals[(size_t)b * 256 + tid];
    s_in[tid + 128] = finals[(size_t)b * 256 + 128 + tid];
    __syncthreads();
    float acc = fc1b[tid];
    const float* wrow = &fc1w[tid * 256];
#pragma unroll 8
    for (int i = 0; i < 256; ++i) acc += s_in[i] * wrow[i];
    s_h1[tid] = fmaxf(acc, 0.0f);
    __syncthreads();
    if (tid < 2) {
        float a = fc2b[tid];
        const float* w2 = &fc2w[tid * 128];
#pragma unroll 8
        for (int i = 0; i < 128; ++i) a += s_h1[i] * w2[i];
        out[b * 2 + tid] = a;
    }
}

extern "C" void kernel_launch(void* const* d_in, const int* in_sizes, int n_in,
                              void* d_out, int out_size, void* d_ws, size_t ws_size,
                              hipStream_t stream) {
    const float* x      = (const float*)d_in[0];
    const float* wih0f  = (const float*)d_in[1];
    const float* whh0f  = (const float*)d_in[2];
    const float* bih0f  = (const float*)d_in[3];
    const float* bhh0f  = (const float*)d_in[4];
    const float* wih0b  = (const float*)d_in[5];
    const float* whh0b  = (const float*)d_in[6];
    const float* bih0b  = (const float*)d_in[7];
    const float* bhh0b  = (const float*)d_in[8];
    const float* wih1f  = (const float*)d_in[9];
    const float* whh1f  = (const float*)d_in[10];
    const float* bih1f  = (const float*)d_in[11];
    const float* bhh1f  = (const float*)d_in[12];
    const float* wih1b  = (const float*)d_in[13];
    const float* whh1b  = (const float*)d_in[14];
    const float* bih1b  = (const float*)d_in[15];
    const float* bhh1b  = (const float*)d_in[16];
    const float* fc1w   = (const float*)d_in[17];
    const float* fc1b   = (const float*)d_in[18];
    const float* fc2w   = (const float*)d_in[19];
    const float* fc2b   = (const float*)d_in[20];

    const size_t Y0SZ = 134217728ull;   // y0 bf16 [512][512][256]
    const size_t HSSZ = 524288ull;      // hstate/finals f32 [512][256]
    const size_t WCSZ = 393216ull;      // wcat bf16 [768][256]
    const size_t BCSZ = 3072ull;        // bcat f32 [768]
    const size_t GX_PER_SL = 786432ull; // per sl: 2 dirs * 512 * 384 bf16 * 2B

    unsigned short* y0 = (unsigned short*)d_ws;
    float*  hstate = (float*)((char*)d_ws + Y0SZ);
    unsigned short* wcat = (unsigned short*)((char*)d_ws + Y0SZ + HSSZ);
    float*  bcat   = (float*)((char*)d_ws + Y0SZ + HSSZ + WCSZ);
    unsigned short* gxc = (unsigned short*)((char*)d_ws + Y0SZ + HSSZ + WCSZ + BCSZ);
    float* out = (float*)d_out;

    int CT = 0;
    const int cts[6] = {128, 64, 32, 16, 8, 4};
    for (int i = 0; i < 6; ++i) {
        if (Y0SZ + HSSZ + WCSZ + BCSZ + (size_t)cts[i] * GX_PER_SL <= ws_size) {
            CT = cts[i];
            break;
        }
    }

    if (CT > 0) {
        w_prep<<<dim3(768), dim3(256), 0, stream>>>(wih1f, wih1b, bih1f, bih1b, wcat, bcat);
        gru_l0<<<dim3(64), dim3(THREADS), 0, stream>>>(
            x, wih0f, whh0f, bih0f, bhh0f, wih0b, whh0b, bih0b, bhh0b, y0);
        const int nchunks = Tt / CT;
        for (int kc = 0; kc < nchunks; ++kc) {
            gx_gemm<<<dim3(24 * CT), dim3(256), 0, stream>>>(
                y0, wcat, bcat, gxc, kc, CT);
            gru_l1c<<<dim3(64), dim3(THREADS), 0, stream>>>(
                gxc, whh1f, bhh1f, whh1b, bhh1b, hstate, CT, (kc == 0) ? 1 : 0);
        }
        fc_head<<<dim3(Bb), dim3(128), 0, stream>>>(hstate, fc1w, fc1b, fc2w, fc2b, out);
    } else {
        float* finals = (float*)((char*)d_ws + Y0SZ);
        gru_l0<<<dim3(64), dim3(THREADS), 0, stream>>>(
            x, wih0f, whh0f, bih0f, bhh0f, wih0b, whh0b, bih0b, bhh0b, y0);
        gru_l1<<<dim3(64), dim3(THREADS), 0, stream>>>(
            y0, wih1f, whh1f, bih1f, bhh1f, wih1b, whh1b, bih1b, bhh1b, finals);
        fc_head<<<dim3(Bb), dim3(128), 0, stream>>>(finals, fc1w, fc1b, fc2w, fc2b, out);
    }
}

// Round 8
// 1213.629 us; speedup vs baseline: 1.7585x; 1.0948x over previous
//
#include <hip/hip_runtime.h>
#include <stdint.h>

// GRUClassifier: 2-layer bidir GRU (H=128, T=512, B=512) + FC head.
// R8: overlap the Gx GEMM with the scan. One fused kernel per chunk:
// blocks [0,64) run scan(k) on 64 CUs reading gx ping-pong buf[k&1];
// blocks [64,..) run gemm(k+1) on the other 192 CUs writing buf[(k+1)&1].
// No intra-launch dependency (scan reads prior launch's gemm output).
// Gemm role is the R7-validated 128x128 tile, re-waved for 512 threads.

#define Tt 512
#define Bb 512
#define THREADS 512

using s16x8 = __attribute__((ext_vector_type(8))) short;  // 8 bf16 (4 VGPRs)
using f32x4 = __attribute__((ext_vector_type(4))) float;

#define MF(a, b, c) __builtin_amdgcn_mfma_f32_16x16x32_bf16((a), (b), (c), 0, 0, 0)

__device__ __forceinline__ unsigned short f2bf(float f) {
    union { float f; unsigned int u; } v; v.f = f;
    unsigned int u = v.u;
    u += 0x7fffu + ((u >> 16) & 1u);   // RNE
    return (unsigned short)(u >> 16);
}
__device__ __forceinline__ float bf2f(unsigned short h) {
    union { unsigned int u; float f; } v; v.u = ((unsigned int)h) << 16;
    return v.f;
}

__device__ __forceinline__ float fsig(float x) {
    return __builtin_amdgcn_rcpf(1.0f + __expf(-x));
}
__device__ __forceinline__ float ftanh(float x) {
    return 2.0f * __builtin_amdgcn_rcpf(1.0f + __expf(-2.0f * x)) - 1.0f;
}

// Raw workgroup barrier: drains LDS ops only; in-flight global register
// prefetch loads survive it (vmcnt not drained).
#define WG_BARRIER() asm volatile("s_waitcnt lgkmcnt(0)\n\ts_barrier" ::: "memory")

// ---------------------------------------------------------------------------
// w_prep: pack W_ih1 (both dirs) to bf16 [768][256] + bias concat [768].
// ---------------------------------------------------------------------------
__global__ void w_prep(const float* __restrict__ wihf, const float* __restrict__ wihb,
                       const float* __restrict__ bihf, const float* __restrict__ bihb,
                       unsigned short* __restrict__ wcat, float* __restrict__ bcat)
{
    const int n = blockIdx.x;   // 0..767
    const int k = threadIdx.x;  // 0..255
    const float* src = (n < 384) ? &wihf[(size_t)n * 256] : &wihb[(size_t)(n - 384) * 256];
    wcat[(size_t)n * 256 + k] = f2bf(src[k]);
    if (k == 0) bcat[n] = (n < 384) ? bihf[n] : bihb[n - 384];
}

// ---------------------------------------------------------------------------
// l1_step: fused chunk kernel.
//   blocks [0,nscan): scan role, chunk kscan, reads gx_rd.
//     grid-part = 64 (dir*32+chunk); h-state relayed via hstate (fp32).
//   blocks [nscan,..): gemm role, chunk kgemm, writes gx_wr.
//     tile = (dir, sl, 128-row batch tile, 128-col gate tile); K=256 in two
//     128-halves; layout gx[(dir*CT+sl)*512 + b]*384 + gc (gc = gate*128+col).
// ---------------------------------------------------------------------------
__global__ __launch_bounds__(THREADS) void l1_step(
    const unsigned short* __restrict__ y0,
    const unsigned short* __restrict__ wcat,
    const float* __restrict__ bcat,
    const unsigned short* __restrict__ gx_rd,
    unsigned short* __restrict__ gx_wr,
    const float* __restrict__ whh_f, const float* __restrict__ bhh_f,
    const float* __restrict__ whh_b, const float* __restrict__ bhh_b,
    float* __restrict__ hstate,
    int CT, int kgemm, int nscan, int first)
{
    const int bid  = blockIdx.x;
    const int tid  = threadIdx.x;
    const int wave = tid >> 6;
    const int lane = tid & 63;
    const int lcol = lane & 15;
    const int quad = lane >> 4;

    __shared__ __align__(16) unsigned short lA[128][136];
    __shared__ __align__(16) unsigned short lB[128][136];
    __shared__ __align__(16) unsigned short lds_h[2][16][136];

    if (bid >= nscan) {
        // =============================== GEMM role ===========================
        int gb = bid - nscan;
        const int nt = gb % 3;  gb /= 3;
        const int bt = gb & 3;  gb >>= 2;
        const int sl = gb % CT;
        const int dir = gb / CT;
        const int s  = kgemm * CT + sl;
        const int t  = dir ? (511 - s) : s;
        const int bb = bt << 7;

        const unsigned short* Abase = y0 + ((size_t)t * 512 + bb) * 256;
        const unsigned short* Bbase = wcat + ((size_t)dir * 384 + nt * 128) * 256;

        const int r0 = (wave >> 2) * 64;   // 0 or 64
        const int c0 = (wave & 3) * 32;    // 0,32,64,96

        f32x4 acc[4][2];
#pragma unroll
        for (int ti = 0; ti < 4; ++ti)
#pragma unroll
            for (int tj = 0; tj < 2; ++tj) acc[ti][tj] = {0.f, 0.f, 0.f, 0.f};

        const int rstg = tid >> 4;         // 0..31
        const int cstg = (tid & 15) * 8;   // 0..120 (<136)

#pragma unroll
        for (int kh = 0; kh < 2; ++kh) {
            if (kh) __syncthreads();
#pragma unroll
            for (int it = 0; it < 4; ++it) {
                const int r = it * 32 + rstg;
                *(ulonglong2*)&lA[r][cstg] =
                    *(const ulonglong2*)&Abase[(size_t)r * 256 + kh * 128 + cstg];
                *(ulonglong2*)&lB[r][cstg] =
                    *(const ulonglong2*)&Bbase[(size_t)r * 256 + kh * 128 + cstg];
            }
            __syncthreads();

#pragma unroll
            for (int kk = 0; kk < 4; ++kk) {
                s16x8 af[4], bfv[2];
#pragma unroll
                for (int ti = 0; ti < 4; ++ti)
                    af[ti] = *(const s16x8*)&lA[r0 + ti * 16 + lcol][kk * 32 + quad * 8];
#pragma unroll
                for (int tj = 0; tj < 2; ++tj)
                    bfv[tj] = *(const s16x8*)&lB[c0 + tj * 16 + lcol][kk * 32 + quad * 8];
#pragma unroll
                for (int ti = 0; ti < 4; ++ti)
#pragma unroll
                    for (int tj = 0; tj < 2; ++tj)
                        acc[ti][tj] = MF(af[ti], bfv[tj], acc[ti][tj]);
            }
        }

        float bias[2];
#pragma unroll
        for (int tj = 0; tj < 2; ++tj)
            bias[tj] = bcat[dir * 384 + nt * 128 + c0 + tj * 16 + lcol];

        __syncthreads();   // fragment reads done; reuse lA as C staging

        unsigned short* lC = &lA[0][0];
#pragma unroll
        for (int ti = 0; ti < 4; ++ti)
#pragma unroll
            for (int tj = 0; tj < 2; ++tj) {
                const int col = c0 + tj * 16 + lcol;
#pragma unroll
                for (int i = 0; i < 4; ++i)
                    lC[(size_t)(r0 + ti * 16 + 4 * quad + i) * 136 + col] =
                        f2bf(acc[ti][tj][i] + bias[tj]);
            }
        __syncthreads();

        unsigned short* ob = gx_wr + ((size_t)(dir * CT + sl) * 512 + bb) * 384 + nt * 128;
#pragma unroll
        for (int it = 0; it < 4; ++it) {
            const int r = it * 32 + rstg;
            *(ulonglong2*)&ob[(size_t)r * 384 + cstg] =
                *(const ulonglong2*)&lC[(size_t)r * 136 + cstg];
        }
        return;
    }

    // ================================ SCAN role ==============================
    const int dir   = bid >> 5;
    const int chunk = bid & 31;
    const int b0    = chunk * 16;
    const int c     = 16 * wave + lcol;

    const float* whh = dir ? whh_b : whh_f;
    const float* bhh = dir ? bhh_b : bhh_f;

    const float bhr = bhh[c];
    const float bhz = bhh[128 + c];
    const float bhn = bhh[256 + c];

    s16x8 bh[3][4];
#pragma unroll
    for (int p = 0; p < 3; ++p) {
        const int nrow = p * 128 + c;
#pragma unroll
        for (int kk = 0; kk < 4; ++kk) {
            const float* src = &whh[(size_t)nrow * 128 + kk * 32 + quad * 8];
            s16x8 f;
#pragma unroll
            for (int j = 0; j < 8; ++j) f[j] = (short)f2bf(src[j]);
            bh[p][kk] = f;
        }
    }

    const unsigned short* gbase = gx_rd + (size_t)dir * CT * 512 * 384;
    auto loadGX = [&](unsigned short (&G)[12], int sl) {
        const unsigned short* gp = gbase + ((size_t)sl * 512 + b0 + 4 * quad) * 384;
#pragma unroll
        for (int g = 0; g < 3; ++g)
#pragma unroll
            for (int i = 0; i < 4; ++i)
                G[g * 4 + i] = gp[(size_t)i * 384 + g * 128 + c];
    };
    unsigned short G0[12], G1[12];
    loadGX(G0, 0);
    loadGX(G1, 1);

    float hreg[4];
    const int gb2 = tid >> 5;          // 0..15 batch row for LDS init
    const int j0  = (tid & 31) * 4;    // 0..124
    if (first) {
#pragma unroll
        for (int i = 0; i < 4; ++i) hreg[i] = 0.f;
        ushort4 z4; z4.x = 0; z4.y = 0; z4.z = 0; z4.w = 0;
        *(ushort4*)&lds_h[0][gb2][j0] = z4;
    } else {
#pragma unroll
        for (int i = 0; i < 4; ++i)
            hreg[i] = hstate[(size_t)(b0 + 4 * quad + i) * 256 + dir * 128 + c];
        ushort4 hv;
        hv.x = f2bf(hstate[(size_t)(b0 + gb2) * 256 + dir * 128 + j0 + 0]);
        hv.y = f2bf(hstate[(size_t)(b0 + gb2) * 256 + dir * 128 + j0 + 1]);
        hv.z = f2bf(hstate[(size_t)(b0 + gb2) * 256 + dir * 128 + j0 + 2]);
        hv.w = f2bf(hstate[(size_t)(b0 + gb2) * 256 + dir * 128 + j0 + 3]);
        *(ushort4*)&lds_h[0][gb2][j0] = hv;
    }
    __syncthreads();

#define L1C_STEP(S, PAR, G)                                                    \
    do {                                                                       \
        const s16x8 a0 = *(const s16x8*)&lds_h[PAR][lcol][0  + quad * 8];      \
        const s16x8 a1 = *(const s16x8*)&lds_h[PAR][lcol][32 + quad * 8];      \
        const s16x8 a2 = *(const s16x8*)&lds_h[PAR][lcol][64 + quad * 8];      \
        const s16x8 a3 = *(const s16x8*)&lds_h[PAR][lcol][96 + quad * 8];      \
        f32x4 rA = {bhr, bhr, bhr, bhr}, rB = {0.f, 0.f, 0.f, 0.f};            \
        f32x4 zA = {bhz, bhz, bhz, bhz}, zB = {0.f, 0.f, 0.f, 0.f};            \
        f32x4 nA = {bhn, bhn, bhn, bhn}, nB = {0.f, 0.f, 0.f, 0.f};            \
        rA = MF(a0, bh[0][0], rA); zA = MF(a0, bh[1][0], zA);                  \
        nA = MF(a0, bh[2][0], nA);                                             \
        rB = MF(a1, bh[0][1], rB); zB = MF(a1, bh[1][1], zB);                  \
        nB = MF(a1, bh[2][1], nB);                                             \
        rA = MF(a2, bh[0][2], rA); zA = MF(a2, bh[1][2], zA);                  \
        nA = MF(a2, bh[2][2], nA);                                             \
        rB = MF(a3, bh[0][3], rB); zB = MF(a3, bh[1][3], zB);                  \
        nB = MF(a3, bh[2][3], nB);                                             \
        _Pragma("unroll")                                                      \
        for (int i = 0; i < 4; ++i) {                                          \
            const float r = fsig(rA[i] + rB[i] + bf2f(G[i]));                  \
            const float z = fsig(zA[i] + zB[i] + bf2f(G[4 + i]));              \
            const float n = ftanh(bf2f(G[8 + i]) + r * (nA[i] + nB[i]));       \
            hreg[i] = (1.0f - z) * n + z * hreg[i];                            \
            lds_h[PAR ^ 1][4 * quad + i][c] = f2bf(hreg[i]);                   \
        }                                                                      \
        if ((S) < CT - 2) {                                                    \
            loadGX(G, (S) + 2);                                                \
        } else if ((S) == CT - 1) {                                            \
            _Pragma("unroll")                                                  \
            for (int i = 0; i < 4; ++i)                                        \
                hstate[(size_t)(b0 + 4 * quad + i) * 256 + dir * 128 + c] =    \
                    hreg[i];                                                   \
        }                                                                      \
        WG_BARRIER();                                                          \
    } while (0)

    for (int sl = 0; sl < CT; sl += 2) {
        L1C_STEP(sl,     0, G0);
        L1C_STEP(sl + 1, 1, G1);
    }
#undef L1C_STEP
}

// ---------------------------------------------------------------------------
// Fallback layer-1 (fused Gx, verbatim from passing R3) — if no CT fits.
// ---------------------------------------------------------------------------
__global__ __launch_bounds__(THREADS, 1) void gru_l1(
    const unsigned short* __restrict__ y0,
    const float* __restrict__ wih_f, const float* __restrict__ whh_f,
    const float* __restrict__ bih_f, const float* __restrict__ bhh_f,
    const float* __restrict__ wih_b, const float* __restrict__ whh_b,
    const float* __restrict__ bih_b, const float* __restrict__ bhh_b,
    float* __restrict__ finals)
{
    const int tid  = threadIdx.x;
    const int wave = tid >> 6;
    const int lane = tid & 63;
    const int lcol = lane & 15;
    const int quad = lane >> 4;
    const int dir   = blockIdx.x >> 5;
    const int b0    = (blockIdx.x & 31) * 16;
    const int c     = 16 * wave + lcol;

    const float* wih = dir ? wih_b : wih_f;
    const float* whh = dir ? whh_b : whh_f;
    const float* bih = dir ? bih_b : bih_f;
    const float* bhh = dir ? bhh_b : bhh_f;

    __shared__ __align__(16) unsigned short lds_h[2][16][136];

    const float br  = bih[c]       + bhh[c];
    const float bz  = bih[128 + c] + bhh[128 + c];
    const float bnx = bih[256 + c];
    const float bnh = bhh[256 + c];

    s16x8 bh[3][4];
    s16x8 bx[3][8];
#pragma unroll
    for (int p = 0; p < 3; ++p) {
        const int nrow = p * 128 + c;
#pragma unroll
        for (int kk = 0; kk < 4; ++kk) {
            const float* src = &whh[(size_t)nrow * 128 + kk * 32 + quad * 8];
            s16x8 f;
#pragma unroll
            for (int j = 0; j < 8; ++j) f[j] = (short)f2bf(src[j]);
            bh[p][kk] = f;
        }
#pragma unroll
        for (int kk = 0; kk < 8; ++kk) {
            const float* src = &wih[(size_t)nrow * 256 + kk * 32 + quad * 8];
            s16x8 f;
#pragma unroll
            for (int j = 0; j < 8; ++j) f[j] = (short)f2bf(src[j]);
            bx[p][kk] = f;
        }
    }

    auto loadP = [&](s16x8 (&P)[8], int t) {
        const unsigned short* pb = y0 + ((size_t)t * Bb + b0 + lcol) * 256 + quad * 8;
#pragma unroll
        for (int kk = 0; kk < 8; ++kk) P[kk] = *(const s16x8*)(pb + kk * 32);
    };
    s16x8 P0[8], P1[8];
    loadP(P0, dir ? 511 : 0);
    loadP(P1, dir ? 510 : 1);

    f32x4 accr = {br, br, br, br};
    f32x4 accz = {bz, bz, bz, bz};
    f32x4 accnx = {bnx, bnx, bnx, bnx};
#pragma unroll
    for (int kk = 0; kk < 8; ++kk) {
        accr  = MF(P0[kk], bx[0][kk], accr);
        accz  = MF(P0[kk], bx[1][kk], accz);
        accnx = MF(P0[kk], bx[2][kk], accnx);
    }
    loadP(P0, dir ? 509 : 2);

    float hreg[4] = {0.f, 0.f, 0.f, 0.f};
    for (int idx = tid; idx < 2 * 16 * 136; idx += THREADS)
        ((unsigned short*)lds_h)[idx] = 0;
    __syncthreads();

#define L1_STEP(S, PAR, PN)                                                    \
    do {                                                                       \
        const s16x8 a0 = *(const s16x8*)&lds_h[PAR][lcol][0  + quad * 8];      \
        const s16x8 a1 = *(const s16x8*)&lds_h[PAR][lcol][32 + quad * 8];      \
        const s16x8 a2 = *(const s16x8*)&lds_h[PAR][lcol][64 + quad * 8];      \
        const s16x8 a3 = *(const s16x8*)&lds_h[PAR][lcol][96 + quad * 8];      \
        f32x4 acchn = {bnh, bnh, bnh, bnh};                                    \
        accr = MF(a0, bh[0][0], accr); accz = MF(a0, bh[1][0], accz);          \
        acchn = MF(a0, bh[2][0], acchn);                                       \
        accr = MF(a1, bh[0][1], accr); accz = MF(a1, bh[1][1], accz);          \
        acchn = MF(a1, bh[2][1], acchn);                                       \
        accr = MF(a2, bh[0][2], accr); accz = MF(a2, bh[1][2], accz);          \
        acchn = MF(a2, bh[2][2], acchn);                                       \
        accr = MF(a3, bh[0][3], accr); accz = MF(a3, bh[1][3], accz);          \
        acchn = MF(a3, bh[2][3], acchn);                                       \
        _Pragma("unroll")                                                      \
        for (int i = 0; i < 4; ++i) {                                          \
            const float r = fsig(accr[i]);                                     \
            const float z = fsig(accz[i]);                                     \
            const float n = ftanh(accnx[i] + r * acchn[i]);                    \
            hreg[i] = (1.0f - z) * n + z * hreg[i];                            \
            lds_h[PAR ^ 1][4 * quad + i][c] = f2bf(hreg[i]);                   \
        }                                                                      \
        if ((S) < 511) {                                                       \
            accr = {br, br, br, br}; accz = {bz, bz, bz, bz};                  \
            accnx = {bnx, bnx, bnx, bnx};                                      \
            _Pragma("unroll")                                                  \
            for (int kk = 0; kk < 8; ++kk) {                                   \
                accr  = MF(PN[kk], bx[0][kk], accr);                           \
                accz  = MF(PN[kk], bx[1][kk], accz);                           \
                accnx = MF(PN[kk], bx[2][kk], accnx);                          \
            }                                                                  \
            int sp = (S) + 3; if (sp > 511) sp = 511;                          \
            loadP(PN, dir ? (511 - sp) : sp);                                  \
        } else {                                                               \
            _Pragma("unroll")                                                  \
            for (int i = 0; i < 4; ++i)                                        \
                finals[(size_t)(b0 + 4 * quad + i) * 256 + dir * 128 + c] =    \
                    hreg[i];                                                   \
        }                                                                      \
        WG_BARRIER();                                                          \
    } while (0)

    for (int s = 0; s < Tt; s += 2) {
        L1_STEP(s,     0, P1);
        L1_STEP(s + 1, 1, P0);
    }
#undef L1_STEP
}

// ---------------------------------------------------------------------------
// Layer 0 scan (verbatim from passing R3/R7): K=4 scalar x-proj + MFMA Gh.
// ---------------------------------------------------------------------------
__global__ __launch_bounds__(THREADS, 1) void gru_l0(
    const float* __restrict__ x,
    const float* __restrict__ wih_f, const float* __restrict__ whh_f,
    const float* __restrict__ bih_f, const float* __restrict__ bhh_f,
    const float* __restrict__ wih_b, const float* __restrict__ whh_b,
    const float* __restrict__ bih_b, const float* __restrict__ bhh_b,
    unsigned short* __restrict__ y0)
{
    const int tid  = threadIdx.x;
    const int wave = tid >> 6;
    const int lane = tid & 63;
    const int lcol = lane & 15;
    const int quad = lane >> 4;
    const int dir   = blockIdx.x >> 5;
    const int b0    = (blockIdx.x & 31) * 16;
    const int c     = 16 * wave + lcol;

    const float* wih = dir ? wih_b : wih_f;
    const float* whh = dir ? whh_b : whh_f;
    const float* bih = dir ? bih_b : bih_f;
    const float* bhh = dir ? bhh_b : bhh_f;

    __shared__ __align__(16) unsigned short lds_h[2][16][136];

    const float brs  = bih[c]       + bhh[c];
    const float bzs  = bih[128 + c] + bhh[128 + c];
    const float bnxs = bih[256 + c];
    const float bnh  = bhh[256 + c];

    float wr[4], wz[4], wn[4];
#pragma unroll
    for (int f = 0; f < 4; ++f) {
        wr[f] = wih[(c)       * 4 + f];
        wz[f] = wih[(128 + c) * 4 + f];
        wn[f] = wih[(256 + c) * 4 + f];
    }

    s16x8 bh[3][4];
#pragma unroll
    for (int p = 0; p < 3; ++p) {
        const int nrow = p * 128 + c;
#pragma unroll
        for (int kk = 0; kk < 4; ++kk) {
            const float* src = &whh[(size_t)nrow * 128 + kk * 32 + quad * 8];
            s16x8 f;
#pragma unroll
            for (int j = 0; j < 8; ++j) f[j] = (short)f2bf(src[j]);
            bh[p][kk] = f;
        }
    }

    auto loadX = [&](float4 (&X)[4], int t) {
#pragma unroll
        for (int i = 0; i < 4; ++i)
            X[i] = *(const float4*)&x[((size_t)(b0 + 4 * quad + i) * Tt + t) * 4];
    };
    float4 X0[4], X1[4];
    loadX(X0, dir ? 511 : 0);
    loadX(X1, dir ? 510 : 1);

    float xpr[4], xpz[4], xpn[4];
#pragma unroll
    for (int i = 0; i < 4; ++i) {
        xpr[i] = brs  + X0[i].x * wr[0] + X0[i].y * wr[1] + X0[i].z * wr[2] + X0[i].w * wr[3];
        xpz[i] = bzs  + X0[i].x * wz[0] + X0[i].y * wz[1] + X0[i].z * wz[2] + X0[i].w * wz[3];
        xpn[i] = bnxs + X0[i].x * wn[0] + X0[i].y * wn[1] + X0[i].z * wn[2] + X0[i].w * wn[3];
    }
    loadX(X0, dir ? 509 : 2);

    float hreg[4] = {0.f, 0.f, 0.f, 0.f};
    for (int idx = tid; idx < 2 * 16 * 136; idx += THREADS)
        ((unsigned short*)lds_h)[idx] = 0;
    __syncthreads();

    const int orow = tid >> 5;
    const int oc4  = (tid & 31) * 4;

#define L0_STEP(S, PAR, XN)                                                    \
    do {                                                                       \
        const int t = dir ? (511 - (S)) : (S);                                 \
        const s16x8 a0 = *(const s16x8*)&lds_h[PAR][lcol][0  + quad * 8];      \
        const s16x8 a1 = *(const s16x8*)&lds_h[PAR][lcol][32 + quad * 8];      \
        const s16x8 a2 = *(const s16x8*)&lds_h[PAR][lcol][64 + quad * 8];      \
        const s16x8 a3 = *(const s16x8*)&lds_h[PAR][lcol][96 + quad * 8];      \
        f32x4 accr  = {xpr[0], xpr[1], xpr[2], xpr[3]};                        \
        f32x4 accz  = {xpz[0], xpz[1], xpz[2], xpz[3]};                        \
        f32x4 acchn = {bnh, bnh, bnh, bnh};                                    \
        accr = MF(a0, bh[0][0], accr); accz = MF(a0, bh[1][0], accz);          \
        acchn = MF(a0, bh[2][0], acchn);                                       \
        accr = MF(a1, bh[0][1], accr); accz = MF(a1, bh[1][1], accz);          \
        acchn = MF(a1, bh[2][1], acchn);                                       \
        accr = MF(a2, bh[0][2], accr); accz = MF(a2, bh[1][2], accz);          \
        acchn = MF(a2, bh[2][2], acchn);                                       \
        accr = MF(a3, bh[0][3], accr); accz = MF(a3, bh[1][3], accz);          \
        acchn = MF(a3, bh[2][3], acchn);                                       \
        _Pragma("unroll")                                                      \
        for (int i = 0; i < 4; ++i) {                                          \
            const float r = fsig(accr[i]);                                     \
            const float z = fsig(accz[i]);                                     \
            const float n = ftanh(xpn[i] + r * acchn[i]);                      \
            hreg[i] = (1.0f - z) * n + z * hreg[i];                            \
            lds_h[PAR ^ 1][4 * quad + i][c] = f2bf(hreg[i]);                   \
        }                                                                      \
        if ((S) < 511) {                                                       \
            _Pragma("unroll")                                                  \
            for (int i = 0; i < 4; ++i) {                                      \
                xpr[i] = brs  + XN[i].x * wr[0] + XN[i].y * wr[1]              \
                              + XN[i].z * wr[2] + XN[i].w * wr[3];             \
                xpz[i] = bzs  + XN[i].x * wz[0] + XN[i].y * wz[1]              \
                              + XN[i].z * wz[2] + XN[i].w * wz[3];             \
                xpn[i] = bnxs + XN[i].x * wn[0] + XN[i].y * wn[1]              \
                              + XN[i].z * wn[2] + XN[i].w * wn[3];             \
            }                                                                  \
            int sp = (S) + 3; if (sp > 511) sp = 511;                          \
            loadX(XN, dir ? (511 - sp) : sp);                                  \
        }                                                                      \
        WG_BARRIER();                                                          \
        {                                                                      \
            const ushort4 hv4 = *(const ushort4*)&lds_h[PAR ^ 1][orow][oc4];   \
            *(ushort4*)&y0[((size_t)t * Bb + b0 + orow) * 256 + dir * 128 +    \
                           oc4] = hv4;                                         \
        }                                                                      \
    } while (0)

    for (int s = 0; s < Tt; s += 2) {
        L0_STEP(s,     0, X1);
        L0_STEP(s + 1, 1, X0);
    }
#undef L0_STEP
}

// ---------------------------------------------------------------------------
// FC head: out = relu(finals @ fc1^T + b1) @ fc2^T + b2   [512,256]->[512,2]
// ---------------------------------------------------------------------------
__global__ __launch_bounds__(128) void fc_head(
    const float* __restrict__ finals,
    const float* __restrict__ fc1w, const float* __restrict__ fc1b,
    const float* __restrict__ fc2w, const float* __restrict__ fc2b,
    float* __restrict__ out)
{
    __shared__ float s_in[256];
    __shared__ float s_h1[128];
    const int b = blockIdx.x, tid = threadIdx.x;
    s_in[tid]       = finals[(size_t)b * 256 + tid];
    s_in[tid + 128] = finals[(size_t)b * 256 + 128 + tid];
    __syncthreads();
    float acc = fc1b[tid];
    const float* wrow = &fc1w[tid * 256];
#pragma unroll 8
    for (int i = 0; i < 256; ++i) acc += s_in[i] * wrow[i];
    s_h1[tid] = fmaxf(acc, 0.0f);
    __syncthreads();
    if (tid < 2) {
        float a = fc2b[tid];
        const float* w2 = &fc2w[tid * 128];
#pragma unroll 8
        for (int i = 0; i < 128; ++i) a += s_h1[i] * w2[i];
        out[b * 2 + tid] = a;
    }
}

extern "C" void kernel_launch(void* const* d_in, const int* in_sizes, int n_in,
                              void* d_out, int out_size, void* d_ws, size_t ws_size,
                              hipStream_t stream) {
    const float* x      = (const float*)d_in[0];
    const float* wih0f  = (const float*)d_in[1];
    const float* whh0f  = (const float*)d_in[2];
    const float* bih0f  = (const float*)d_in[3];
    const float* bhh0f  = (const float*)d_in[4];
    const float* wih0b  = (const float*)d_in[5];
    const float* whh0b  = (const float*)d_in[6];
    const float* bih0b  = (const float*)d_in[7];
    const float* bhh0b  = (const float*)d_in[8];
    const float* wih1f  = (const float*)d_in[9];
    const float* whh1f  = (const float*)d_in[10];
    const float* bih1f  = (const float*)d_in[11];
    const float* bhh1f  = (const float*)d_in[12];
    const float* wih1b  = (const float*)d_in[13];
    const float* whh1b  = (const float*)d_in[14];
    const float* bih1b  = (const float*)d_in[15];
    const float* bhh1b  = (const float*)d_in[16];
    const float* fc1w   = (const float*)d_in[17];
    const float* fc1b   = (const float*)d_in[18];
    const float* fc2w   = (const float*)d_in[19];
    const float* fc2b   = (const float*)d_in[20];

    const size_t Y0SZ = 134217728ull;   // y0 bf16 [512][512][256]
    const size_t HSSZ = 524288ull;      // hstate/finals f32 [512][256]
    const size_t WCSZ = 393216ull;      // wcat bf16 [768][256]
    const size_t BCSZ = 3072ull;        // bcat f32 [768]
    const size_t GX_PER_SL = 786432ull; // per sl: 2 dirs * 512 * 384 bf16 * 2B
    const size_t BASE = Y0SZ + HSSZ + WCSZ + BCSZ;

    unsigned short* y0 = (unsigned short*)d_ws;
    float*  hstate = (float*)((char*)d_ws + Y0SZ);
    unsigned short* wcat = (unsigned short*)((char*)d_ws + Y0SZ + HSSZ);
    float*  bcat   = (float*)((char*)d_ws + Y0SZ + HSSZ + WCSZ);
    unsigned short* gx0 = (unsigned short*)((char*)d_ws + BASE);
    float* out = (float*)d_out;

    const int cts[6] = {128, 64, 32, 16, 8, 4};
    int CT = 0, fused = 0;
    for (int i = 0; i < 6; ++i)
        if (BASE + 2ull * cts[i] * GX_PER_SL <= ws_size) { CT = cts[i]; fused = 1; break; }
    if (!CT)
        for (int i = 0; i < 6; ++i)
            if (BASE + (size_t)cts[i] * GX_PER_SL <= ws_size) { CT = cts[i]; break; }

    if (CT > 0) {
        unsigned short* gxb[2];
        gxb[0] = gx0;
        gxb[1] = fused ? (unsigned short*)((char*)gx0 + (size_t)CT * GX_PER_SL) : gx0;

        w_prep<<<dim3(768), dim3(256), 0, stream>>>(wih1f, wih1b, bih1f, bih1b, wcat, bcat);
        gru_l0<<<dim3(64), dim3(THREADS), 0, stream>>>(
            x, wih0f, whh0f, bih0f, bhh0f, wih0b, whh0b, bih0b, bhh0b, y0);
        const int n = Tt / CT;
        if (fused) {
            // prologue: gemm chunk 0 -> buf0
            l1_step<<<dim3(24 * CT), dim3(THREADS), 0, stream>>>(
                y0, wcat, bcat, gxb[0], gxb[0],
                whh1f, bhh1f, whh1b, bhh1b, hstate, CT, 0, 0, 1);
            for (int k = 0; k < n; ++k) {
                const int ng = (k + 1 < n) ? 24 * CT : 0;
                l1_step<<<dim3(64 + ng), dim3(THREADS), 0, stream>>>(
                    y0, wcat, bcat, gxb[k & 1], gxb[(k + 1) & 1],
                    whh1f, bhh1f, whh1b, bhh1b, hstate, CT, k + 1, 64, (k == 0) ? 1 : 0);
            }
        } else {
            for (int k = 0; k < n; ++k) {
                l1_step<<<dim3(24 * CT), dim3(THREADS), 0, stream>>>(
                    y0, wcat, bcat, gxb[0], gxb[0],
                    whh1f, bhh1f, whh1b, bhh1b, hstate, CT, k, 0, 1);
                l1_step<<<dim3(64), dim3(THREADS), 0, stream>>>(
                    y0, wcat, bcat, gxb[0], gxb[0],
                    whh1f, bhh1f, whh1b, bhh1b, hstate, CT, 0, 64, (k == 0) ? 1 : 0);
            }
        }
        fc_head<<<dim3(Bb), dim3(128), 0, stream>>>(hstate, fc1w, fc1b, fc2w, fc2b, out);
    } else {
        float* finals = (float*)((char*)d_ws + Y0SZ);
        gru_l0<<<dim3(64), dim3(THREADS), 0, stream>>>(
            x, wih0f, whh0f, bih0f, bhh0f, wih0b, whh0b, bih0b, bhh0b, y0);
        gru_l1<<<dim3(64), dim3(THREADS), 0, stream>>>(
            y0, wih1f, whh1f, bih1f, bhh1f, wih1b, whh1b, bih1b, bhh1b, finals);
        fc_head<<<dim3(Bb), dim3(128), 0, stream>>>(finals, fc1w, fc1b, fc2w, fc2b, out);
    }
}

// Round 9
// 1149.825 us; speedup vs baseline: 1.8561x; 1.0555x over previous
//
#include <hip/hip_runtime.h>
#include <stdint.h>

// GRUClassifier: 2-layer bidir GRU (H=128, T=512, B=512) + FC head.
// R9: gru_l0 rewritten BC=4 (256 blocks = all CUs) + cross-lane acc
// redistribution (ds_bpermute via __shfl): gate math 4 -> 1 element/lane
// (6 transcendentals/step instead of 24). l1 pipeline verbatim from R8
// (fused scan+next-chunk-gemm, ping-pong gx buffers).

#define Tt 512
#define Bb 512
#define THREADS 512

using s16x8 = __attribute__((ext_vector_type(8))) short;  // 8 bf16 (4 VGPRs)
using f32x4 = __attribute__((ext_vector_type(4))) float;

#define MF(a, b, c) __builtin_amdgcn_mfma_f32_16x16x32_bf16((a), (b), (c), 0, 0, 0)

__device__ __forceinline__ unsigned short f2bf(float f) {
    union { float f; unsigned int u; } v; v.f = f;
    unsigned int u = v.u;
    u += 0x7fffu + ((u >> 16) & 1u);   // RNE
    return (unsigned short)(u >> 16);
}
__device__ __forceinline__ float bf2f(unsigned short h) {
    union { unsigned int u; float f; } v; v.u = ((unsigned int)h) << 16;
    return v.f;
}

__device__ __forceinline__ float fsig(float x) {
    return __builtin_amdgcn_rcpf(1.0f + __expf(-x));
}
__device__ __forceinline__ float ftanh(float x) {
    return 2.0f * __builtin_amdgcn_rcpf(1.0f + __expf(-2.0f * x)) - 1.0f;
}

// Raw workgroup barrier: drains LDS ops only; in-flight global register
// prefetch loads survive it (vmcnt not drained).
#define WG_BARRIER() asm volatile("s_waitcnt lgkmcnt(0)\n\ts_barrier" ::: "memory")

// ---------------------------------------------------------------------------
// w_prep: pack W_ih1 (both dirs) to bf16 [768][256] + bias concat [768].
// ---------------------------------------------------------------------------
__global__ void w_prep(const float* __restrict__ wihf, const float* __restrict__ wihb,
                       const float* __restrict__ bihf, const float* __restrict__ bihb,
                       unsigned short* __restrict__ wcat, float* __restrict__ bcat)
{
    const int n = blockIdx.x;   // 0..767
    const int k = threadIdx.x;  // 0..255
    const float* src = (n < 384) ? &wihf[(size_t)n * 256] : &wihb[(size_t)(n - 384) * 256];
    wcat[(size_t)n * 256 + k] = f2bf(src[k]);
    if (k == 0) bcat[n] = (n < 384) ? bihf[n] : bihb[n - 384];
}

// ---------------------------------------------------------------------------
// l1_step: fused chunk kernel (verbatim R8).
//   blocks [0,nscan): scan role, reads gx_rd. blocks [nscan,..): gemm role,
//   chunk kgemm, writes gx_wr. gx layout [(dir*CT+sl)*512 + b]*384 + gc.
// ---------------------------------------------------------------------------
__global__ __launch_bounds__(THREADS) void l1_step(
    const unsigned short* __restrict__ y0,
    const unsigned short* __restrict__ wcat,
    const float* __restrict__ bcat,
    const unsigned short* __restrict__ gx_rd,
    unsigned short* __restrict__ gx_wr,
    const float* __restrict__ whh_f, const float* __restrict__ bhh_f,
    const float* __restrict__ whh_b, const float* __restrict__ bhh_b,
    float* __restrict__ hstate,
    int CT, int kgemm, int nscan, int first)
{
    const int bid  = blockIdx.x;
    const int tid  = threadIdx.x;
    const int wave = tid >> 6;
    const int lane = tid & 63;
    const int lcol = lane & 15;
    const int quad = lane >> 4;

    __shared__ __align__(16) unsigned short lA[128][136];
    __shared__ __align__(16) unsigned short lB[128][136];
    __shared__ __align__(16) unsigned short lds_h[2][16][136];

    if (bid >= nscan) {
        // =============================== GEMM role ===========================
        int gb = bid - nscan;
        const int nt = gb % 3;  gb /= 3;
        const int bt = gb & 3;  gb >>= 2;
        const int sl = gb % CT;
        const int dir = gb / CT;
        const int s  = kgemm * CT + sl;
        const int t  = dir ? (511 - s) : s;
        const int bb = bt << 7;

        const unsigned short* Abase = y0 + ((size_t)t * 512 + bb) * 256;
        const unsigned short* Bbase = wcat + ((size_t)dir * 384 + nt * 128) * 256;

        const int r0 = (wave >> 2) * 64;   // 0 or 64
        const int c0 = (wave & 3) * 32;    // 0,32,64,96

        f32x4 acc[4][2];
#pragma unroll
        for (int ti = 0; ti < 4; ++ti)
#pragma unroll
            for (int tj = 0; tj < 2; ++tj) acc[ti][tj] = {0.f, 0.f, 0.f, 0.f};

        const int rstg = tid >> 4;         // 0..31
        const int cstg = (tid & 15) * 8;   // 0..120 (<136)

#pragma unroll
        for (int kh = 0; kh < 2; ++kh) {
            if (kh) __syncthreads();
#pragma unroll
            for (int it = 0; it < 4; ++it) {
                const int r = it * 32 + rstg;
                *(ulonglong2*)&lA[r][cstg] =
                    *(const ulonglong2*)&Abase[(size_t)r * 256 + kh * 128 + cstg];
                *(ulonglong2*)&lB[r][cstg] =
                    *(const ulonglong2*)&Bbase[(size_t)r * 256 + kh * 128 + cstg];
            }
            __syncthreads();

#pragma unroll
            for (int kk = 0; kk < 4; ++kk) {
                s16x8 af[4], bfv[2];
#pragma unroll
                for (int ti = 0; ti < 4; ++ti)
                    af[ti] = *(const s16x8*)&lA[r0 + ti * 16 + lcol][kk * 32 + quad * 8];
#pragma unroll
                for (int tj = 0; tj < 2; ++tj)
                    bfv[tj] = *(const s16x8*)&lB[c0 + tj * 16 + lcol][kk * 32 + quad * 8];
#pragma unroll
                for (int ti = 0; ti < 4; ++ti)
#pragma unroll
                    for (int tj = 0; tj < 2; ++tj)
                        acc[ti][tj] = MF(af[ti], bfv[tj], acc[ti][tj]);
            }
        }

        float bias[2];
#pragma unroll
        for (int tj = 0; tj < 2; ++tj)
            bias[tj] = bcat[dir * 384 + nt * 128 + c0 + tj * 16 + lcol];

        __syncthreads();   // fragment reads done; reuse lA as C staging

        unsigned short* lC = &lA[0][0];
#pragma unroll
        for (int ti = 0; ti < 4; ++ti)
#pragma unroll
            for (int tj = 0; tj < 2; ++tj) {
                const int col = c0 + tj * 16 + lcol;
#pragma unroll
                for (int i = 0; i < 4; ++i)
                    lC[(size_t)(r0 + ti * 16 + 4 * quad + i) * 136 + col] =
                        f2bf(acc[ti][tj][i] + bias[tj]);
            }
        __syncthreads();

        unsigned short* ob = gx_wr + ((size_t)(dir * CT + sl) * 512 + bb) * 384 + nt * 128;
#pragma unroll
        for (int it = 0; it < 4; ++it) {
            const int r = it * 32 + rstg;
            *(ulonglong2*)&ob[(size_t)r * 384 + cstg] =
                *(const ulonglong2*)&lC[(size_t)r * 136 + cstg];
        }
        return;
    }

    // ================================ SCAN role ==============================
    const int dir   = bid >> 5;
    const int chunk = bid & 31;
    const int b0    = chunk * 16;
    const int c     = 16 * wave + lcol;

    const float* whh = dir ? whh_b : whh_f;
    const float* bhh = dir ? bhh_b : bhh_f;

    const float bhr = bhh[c];
    const float bhz = bhh[128 + c];
    const float bhn = bhh[256 + c];

    s16x8 bh[3][4];
#pragma unroll
    for (int p = 0; p < 3; ++p) {
        const int nrow = p * 128 + c;
#pragma unroll
        for (int kk = 0; kk < 4; ++kk) {
            const float* src = &whh[(size_t)nrow * 128 + kk * 32 + quad * 8];
            s16x8 f;
#pragma unroll
            for (int j = 0; j < 8; ++j) f[j] = (short)f2bf(src[j]);
            bh[p][kk] = f;
        }
    }

    const unsigned short* gbase = gx_rd + (size_t)dir * CT * 512 * 384;
    auto loadGX = [&](unsigned short (&G)[12], int sl) {
        const unsigned short* gp = gbase + ((size_t)sl * 512 + b0 + 4 * quad) * 384;
#pragma unroll
        for (int g = 0; g < 3; ++g)
#pragma unroll
            for (int i = 0; i < 4; ++i)
                G[g * 4 + i] = gp[(size_t)i * 384 + g * 128 + c];
    };
    unsigned short G0[12], G1[12];
    loadGX(G0, 0);
    loadGX(G1, 1);

    float hreg[4];
    const int gb2 = tid >> 5;          // 0..15 batch row for LDS init
    const int j0  = (tid & 31) * 4;    // 0..124
    if (first) {
#pragma unroll
        for (int i = 0; i < 4; ++i) hreg[i] = 0.f;
        ushort4 z4; z4.x = 0; z4.y = 0; z4.z = 0; z4.w = 0;
        *(ushort4*)&lds_h[0][gb2][j0] = z4;
    } else {
#pragma unroll
        for (int i = 0; i < 4; ++i)
            hreg[i] = hstate[(size_t)(b0 + 4 * quad + i) * 256 + dir * 128 + c];
        ushort4 hv;
        hv.x = f2bf(hstate[(size_t)(b0 + gb2) * 256 + dir * 128 + j0 + 0]);
        hv.y = f2bf(hstate[(size_t)(b0 + gb2) * 256 + dir * 128 + j0 + 1]);
        hv.z = f2bf(hstate[(size_t)(b0 + gb2) * 256 + dir * 128 + j0 + 2]);
        hv.w = f2bf(hstate[(size_t)(b0 + gb2) * 256 + dir * 128 + j0 + 3]);
        *(ushort4*)&lds_h[0][gb2][j0] = hv;
    }
    __syncthreads();

#define L1C_STEP(S, PAR, G)                                                    \
    do {                                                                       \
        const s16x8 a0 = *(const s16x8*)&lds_h[PAR][lcol][0  + quad * 8];      \
        const s16x8 a1 = *(const s16x8*)&lds_h[PAR][lcol][32 + quad * 8];      \
        const s16x8 a2 = *(const s16x8*)&lds_h[PAR][lcol][64 + quad * 8];      \
        const s16x8 a3 = *(const s16x8*)&lds_h[PAR][lcol][96 + quad * 8];      \
        f32x4 rA = {bhr, bhr, bhr, bhr}, rB = {0.f, 0.f, 0.f, 0.f};            \
        f32x4 zA = {bhz, bhz, bhz, bhz}, zB = {0.f, 0.f, 0.f, 0.f};            \
        f32x4 nA = {bhn, bhn, bhn, bhn}, nB = {0.f, 0.f, 0.f, 0.f};            \
        rA = MF(a0, bh[0][0], rA); zA = MF(a0, bh[1][0], zA);                  \
        nA = MF(a0, bh[2][0], nA);                                             \
        rB = MF(a1, bh[0][1], rB); zB = MF(a1, bh[1][1], zB);                  \
        nB = MF(a1, bh[2][1], nB);                                             \
        rA = MF(a2, bh[0][2], rA); zA = MF(a2, bh[1][2], zA);                  \
        nA = MF(a2, bh[2][2], nA);                                             \
        rB = MF(a3, bh[0][3], rB); zB = MF(a3, bh[1][3], zB);                  \
        nB = MF(a3, bh[2][3], nB);                                             \
        _Pragma("unroll")                                                      \
        for (int i = 0; i < 4; ++i) {                                          \
            const float r = fsig(rA[i] + rB[i] + bf2f(G[i]));                  \
            const float z = fsig(zA[i] + zB[i] + bf2f(G[4 + i]));              \
            const float n = ftanh(bf2f(G[8 + i]) + r * (nA[i] + nB[i]));       \
            hreg[i] = (1.0f - z) * n + z * hreg[i];                            \
            lds_h[PAR ^ 1][4 * quad + i][c] = f2bf(hreg[i]);                   \
        }                                                                      \
        if ((S) < CT - 2) {                                                    \
            loadGX(G, (S) + 2);                                                \
        } else if ((S) == CT - 1) {                                            \
            _Pragma("unroll")                                                  \
            for (int i = 0; i < 4; ++i)                                        \
                hstate[(size_t)(b0 + 4 * quad + i) * 256 + dir * 128 + c] =    \
                    hreg[i];                                                   \
        }                                                                      \
        WG_BARRIER();                                                          \
    } while (0)

    for (int sl = 0; sl < CT; sl += 2) {
        L1C_STEP(sl,     0, G0);
        L1C_STEP(sl + 1, 1, G1);
    }
#undef L1C_STEP
}

// ---------------------------------------------------------------------------
// Fallback layer-1 (fused Gx, verbatim from passing R3) — if no CT fits.
// ---------------------------------------------------------------------------
__global__ __launch_bounds__(THREADS, 1) void gru_l1(
    const unsigned short* __restrict__ y0,
    const float* __restrict__ wih_f, const float* __restrict__ whh_f,
    const float* __restrict__ bih_f, const float* __restrict__ bhh_f,
    const float* __restrict__ wih_b, const float* __restrict__ whh_b,
    const float* __restrict__ bih_b, const float* __restrict__ bhh_b,
    float* __restrict__ finals)
{
    const int tid  = threadIdx.x;
    const int wave = tid >> 6;
    const int lane = tid & 63;
    const int lcol = lane & 15;
    const int quad = lane >> 4;
    const int dir   = blockIdx.x >> 5;
    const int b0    = (blockIdx.x & 31) * 16;
    const int c     = 16 * wave + lcol;

    const float* wih = dir ? wih_b : wih_f;
    const float* whh = dir ? whh_b : whh_f;
    const float* bih = dir ? bih_b : bih_f;
    const float* bhh = dir ? bhh_b : bhh_f;

    __shared__ __align__(16) unsigned short lds_h[2][16][136];

    const float br  = bih[c]       + bhh[c];
    const float bz  = bih[128 + c] + bhh[128 + c];
    const float bnx = bih[256 + c];
    const float bnh = bhh[256 + c];

    s16x8 bh[3][4];
    s16x8 bx[3][8];
#pragma unroll
    for (int p = 0; p < 3; ++p) {
        const int nrow = p * 128 + c;
#pragma unroll
        for (int kk = 0; kk < 4; ++kk) {
            const float* src = &whh[(size_t)nrow * 128 + kk * 32 + quad * 8];
            s16x8 f;
#pragma unroll
            for (int j = 0; j < 8; ++j) f[j] = (short)f2bf(src[j]);
            bh[p][kk] = f;
        }
#pragma unroll
        for (int kk = 0; kk < 8; ++kk) {
            const float* src = &wih[(size_t)nrow * 256 + kk * 32 + quad * 8];
            s16x8 f;
#pragma unroll
            for (int j = 0; j < 8; ++j) f[j] = (short)f2bf(src[j]);
            bx[p][kk] = f;
        }
    }

    auto loadP = [&](s16x8 (&P)[8], int t) {
        const unsigned short* pb = y0 + ((size_t)t * Bb + b0 + lcol) * 256 + quad * 8;
#pragma unroll
        for (int kk = 0; kk < 8; ++kk) P[kk] = *(const s16x8*)(pb + kk * 32);
    };
    s16x8 P0[8], P1[8];
    loadP(P0, dir ? 511 : 0);
    loadP(P1, dir ? 510 : 1);

    f32x4 accr = {br, br, br, br};
    f32x4 accz = {bz, bz, bz, bz};
    f32x4 accnx = {bnx, bnx, bnx, bnx};
#pragma unroll
    for (int kk = 0; kk < 8; ++kk) {
        accr  = MF(P0[kk], bx[0][kk], accr);
        accz  = MF(P0[kk], bx[1][kk], accz);
        accnx = MF(P0[kk], bx[2][kk], accnx);
    }
    loadP(P0, dir ? 509 : 2);

    float hreg[4] = {0.f, 0.f, 0.f, 0.f};
    for (int idx = tid; idx < 2 * 16 * 136; idx += THREADS)
        ((unsigned short*)lds_h)[idx] = 0;
    __syncthreads();

#define L1_STEP(S, PAR, PN)                                                    \
    do {                                                                       \
        const s16x8 a0 = *(const s16x8*)&lds_h[PAR][lcol][0  + quad * 8];      \
        const s16x8 a1 = *(const s16x8*)&lds_h[PAR][lcol][32 + quad * 8];      \
        const s16x8 a2 = *(const s16x8*)&lds_h[PAR][lcol][64 + quad * 8];      \
        const s16x8 a3 = *(const s16x8*)&lds_h[PAR][lcol][96 + quad * 8];      \
        f32x4 acchn = {bnh, bnh, bnh, bnh};                                    \
        accr = MF(a0, bh[0][0], accr); accz = MF(a0, bh[1][0], accz);          \
        acchn = MF(a0, bh[2][0], acchn);                                       \
        accr = MF(a1, bh[0][1], accr); accz = MF(a1, bh[1][1], accz);          \
        acchn = MF(a1, bh[2][1], acchn);                                       \
        accr = MF(a2, bh[0][2], accr); accz = MF(a2, bh[1][2], accz);          \
        acchn = MF(a2, bh[2][2], acchn);                                       \
        accr = MF(a3, bh[0][3], accr); accz = MF(a3, bh[1][3], accz);          \
        acchn = MF(a3, bh[2][3], acchn);                                       \
        _Pragma("unroll")                                                      \
        for (int i = 0; i < 4; ++i) {                                          \
            const float r = fsig(accr[i]);                                     \
            const float z = fsig(accz[i]);                                     \
            const float n = ftanh(accnx[i] + r * acchn[i]);                    \
            hreg[i] = (1.0f - z) * n + z * hreg[i];                            \
            lds_h[PAR ^ 1][4 * quad + i][c] = f2bf(hreg[i]);                   \
        }                                                                      \
        if ((S) < 511) {                                                       \
            accr = {br, br, br, br}; accz = {bz, bz, bz, bz};                  \
            accnx = {bnx, bnx, bnx, bnx};                                      \
            _Pragma("unroll")                                                  \
            for (int kk = 0; kk < 8; ++kk) {                                   \
                accr  = MF(PN[kk], bx[0][kk], accr);                           \
                accz  = MF(PN[kk], bx[1][kk], accz);                           \
                accnx = MF(PN[kk], bx[2][kk], accnx);                          \
            }                                                                  \
            int sp = (S) + 3; if (sp > 511) sp = 511;                          \
            loadP(PN, dir ? (511 - sp) : sp);                                  \
        } else {                                                               \
            _Pragma("unroll")                                                  \
            for (int i = 0; i < 4; ++i)                                        \
                finals[(size_t)(b0 + 4 * quad + i) * 256 + dir * 128 + c] =    \
                    hreg[i];                                                   \
        }                                                                      \
        WG_BARRIER();                                                          \
    } while (0)

    for (int s = 0; s < Tt; s += 2) {
        L1_STEP(s,     0, P1);
        L1_STEP(s + 1, 1, P0);
    }
#undef L1_STEP
}

// ---------------------------------------------------------------------------
// Layer 0 scan, R9: BC=4, grid 256 (dir*128+chunk), block 512 (8 waves).
// Wave w owns gate-cols [16w,16w+16); MFMA M=16 with rows 4..15 zero.
// After MFMA, accumulators are redistributed (__shfl from lane lcol) so each
// lane owns exactly ONE element (row=quad, col=c): 6 transcendentals/step.
// ---------------------------------------------------------------------------
__global__ __launch_bounds__(THREADS, 1) void gru_l0(
    const float* __restrict__ x,
    const float* __restrict__ wih_f, const float* __restrict__ whh_f,
    const float* __restrict__ bih_f, const float* __restrict__ bhh_f,
    const float* __restrict__ wih_b, const float* __restrict__ whh_b,
    const float* __restrict__ bih_b, const float* __restrict__ bhh_b,
    unsigned short* __restrict__ y0)
{
    const int tid  = threadIdx.x;
    const int wave = tid >> 6;
    const int lane = tid & 63;
    const int lcol = lane & 15;
    const int quad = lane >> 4;
    const int dir   = blockIdx.x >> 7;
    const int chunk = blockIdx.x & 127;
    const int b0    = chunk * 4;
    const int c     = 16 * wave + lcol;

    const float* wih = dir ? wih_b : wih_f;
    const float* whh = dir ? whh_b : whh_f;
    const float* bih = dir ? bih_b : bih_f;
    const float* bhh = dir ? bhh_b : bhh_f;

    __shared__ __align__(16) unsigned short lds_h[2][16][136];

    const float brs  = bih[c]       + bhh[c];
    const float bzs  = bih[128 + c] + bhh[128 + c];
    const float bnxs = bih[256 + c];
    const float bnh  = bhh[256 + c];

    float wr[4], wz[4], wn[4];
#pragma unroll
    for (int f = 0; f < 4; ++f) {
        wr[f] = wih[(c)       * 4 + f];
        wz[f] = wih[(128 + c) * 4 + f];
        wn[f] = wih[(256 + c) * 4 + f];
    }

    s16x8 bh[3][4];
#pragma unroll
    for (int p = 0; p < 3; ++p) {
        const int nrow = p * 128 + c;
#pragma unroll
        for (int kk = 0; kk < 4; ++kk) {
            const float* src = &whh[(size_t)nrow * 128 + kk * 32 + quad * 8];
            s16x8 f;
#pragma unroll
            for (int j = 0; j < 8; ++j) f[j] = (short)f2bf(src[j]);
            bh[p][kk] = f;
        }
    }

    // X prefetch: rows b0..b0+3, same addresses for every lane (L1 broadcast).
    auto loadX = [&](float4 (&X)[4], int t) {
#pragma unroll
        for (int i = 0; i < 4; ++i)
            X[i] = *(const float4*)&x[((size_t)(b0 + i) * Tt + t) * 4];
    };
    float4 X0[4], X1[4];
    loadX(X0, dir ? 511 : 0);
    loadX(X1, dir ? 510 : 1);

    // x-projection (+ biases) for rows 0..3 at col c (all lanes identical rows)
    float xpr[4], xpz[4], xpn[4];
#pragma unroll
    for (int i = 0; i < 4; ++i) {
        xpr[i] = brs  + X0[i].x * wr[0] + X0[i].y * wr[1] + X0[i].z * wr[2] + X0[i].w * wr[3];
        xpz[i] = bzs  + X0[i].x * wz[0] + X0[i].y * wz[1] + X0[i].z * wz[2] + X0[i].w * wz[3];
        xpn[i] = bnxs + X0[i].x * wn[0] + X0[i].y * wn[1] + X0[i].z * wn[2] + X0[i].w * wn[3];
    }
    loadX(X0, dir ? 509 : 2);

    float hmine = 0.f;   // this lane's h element: (row=quad, col=c)
    for (int idx = tid; idx < 2 * 16 * 136; idx += THREADS)
        ((unsigned short*)lds_h)[idx] = 0;
    __syncthreads();

    const int orow = tid >> 7;        // y0 store: row 0..3
    const int ocol = tid & 127;       // col 0..127

#define L0_STEP(S, PAR, XN)                                                    \
    do {                                                                       \
        const int t = dir ? (511 - (S)) : (S);                                 \
        const s16x8 a0 = *(const s16x8*)&lds_h[PAR][lcol][0  + quad * 8];      \
        const s16x8 a1 = *(const s16x8*)&lds_h[PAR][lcol][32 + quad * 8];      \
        const s16x8 a2 = *(const s16x8*)&lds_h[PAR][lcol][64 + quad * 8];      \
        const s16x8 a3 = *(const s16x8*)&lds_h[PAR][lcol][96 + quad * 8];      \
        f32x4 accr  = {xpr[0], xpr[1], xpr[2], xpr[3]};                        \
        f32x4 accz  = {xpz[0], xpz[1], xpz[2], xpz[3]};                        \
        f32x4 acchn = {bnh, bnh, bnh, bnh};                                    \
        accr = MF(a0, bh[0][0], accr); accz = MF(a0, bh[1][0], accz);          \
        acchn = MF(a0, bh[2][0], acchn);                                       \
        accr = MF(a1, bh[0][1], accr); accz = MF(a1, bh[1][1], accz);          \
        acchn = MF(a1, bh[2][1], acchn);                                       \
        accr = MF(a2, bh[0][2], accr); accz = MF(a2, bh[1][2], accz);          \
        acchn = MF(a2, bh[2][2], acchn);                                       \
        accr = MF(a3, bh[0][3], accr); accz = MF(a3, bh[1][3], accz);          \
        acchn = MF(a3, bh[2][3], acchn);                                       \
        /* redistribute: element (row i, col lcol) lives in lane lcol reg i */ \
        float rr0 = __shfl(accr[0], lcol), rr1 = __shfl(accr[1], lcol);        \
        float rr2 = __shfl(accr[2], lcol), rr3 = __shfl(accr[3], lcol);        \
        float zz0 = __shfl(accz[0], lcol), zz1 = __shfl(accz[1], lcol);        \
        float zz2 = __shfl(accz[2], lcol), zz3 = __shfl(accz[3], lcol);        \
        float hh0 = __shfl(acchn[0], lcol), hh1 = __shfl(acchn[1], lcol);      \
        float hh2 = __shfl(acchn[2], lcol), hh3 = __shfl(acchn[3], lcol);      \
        const float pr = quad == 0 ? rr0 : quad == 1 ? rr1 : quad == 2 ? rr2 : rr3; \
        const float pz = quad == 0 ? zz0 : quad == 1 ? zz1 : quad == 2 ? zz2 : zz3; \
        const float ph = quad == 0 ? hh0 : quad == 1 ? hh1 : quad == 2 ? hh2 : hh3; \
        const float pn = quad == 0 ? xpn[0] : quad == 1 ? xpn[1]               \
                       : quad == 2 ? xpn[2] : xpn[3];                          \
        {                                                                      \
            const float r = fsig(pr);                                          \
            const float z = fsig(pz);                                          \
            const float n = ftanh(pn + r * ph);                                \
            hmine = (1.0f - z) * n + z * hmine;                                \
            lds_h[PAR ^ 1][quad][c] = f2bf(hmine);                             \
        }                                                                      \
        if ((S) < 511) {                                                       \
            _Pragma("unroll")                                                  \
            for (int i = 0; i < 4; ++i) {                                      \
                xpr[i] = brs  + XN[i].x * wr[0] + XN[i].y * wr[1]              \
                              + XN[i].z * wr[2] + XN[i].w * wr[3];             \
                xpz[i] = bzs  + XN[i].x * wz[0] + XN[i].y * wz[1]              \
                              + XN[i].z * wz[2] + XN[i].w * wz[3];             \
                xpn[i] = bnxs + XN[i].x * wn[0] + XN[i].y * wn[1]              \
                              + XN[i].z * wn[2] + XN[i].w * wn[3];             \
            }                                                                  \
            int sp = (S) + 3; if (sp > 511) sp = 511;                          \
            loadX(XN, dir ? (511 - sp) : sp);                                  \
        }                                                                      \
        WG_BARRIER();                                                          \
        {                                                                      \
            /* coalesced y0 store from the buffer just completed */            \
            y0[((size_t)t * Bb + b0 + orow) * 256 + dir * 128 + ocol] =        \
                lds_h[PAR ^ 1][orow][ocol];                                    \
        }                                                                      \
    } while (0)

    for (int s = 0; s < Tt; s += 2) {
        L0_STEP(s,     0, X1);
        L0_STEP(s + 1, 1, X0);
    }
#undef L0_STEP
}

// ---------------------------------------------------------------------------
// FC head: out = relu(finals @ fc1^T + b1) @ fc2^T + b2   [512,256]->[512,2]
// ---------------------------------------------------------------------------
__global__ __launch_bounds__(128) void fc_head(
    const float* __restrict__ finals,
    const float* __restrict__ fc1w, const float* __restrict__ fc1b,
    const float* __restrict__ fc2w, const float* __restrict__ fc2b,
    float* __restrict__ out)
{
    __shared__ float s_in[256];
    __shared__ float s_h1[128];
    const int b = blockIdx.x, tid = threadIdx.x;
    s_in[tid]       = finals[(size_t)b * 256 + tid];
    s_in[tid + 128] = finals[(size_t)b * 256 + 128 + tid];
    __syncthreads();
    float acc = fc1b[tid];
    const float* wrow = &fc1w[tid * 256];
#pragma unroll 8
    for (int i = 0; i < 256; ++i) acc += s_in[i] * wrow[i];
    s_h1[tid] = fmaxf(acc, 0.0f);
    __syncthreads();
    if (tid < 2) {
        float a = fc2b[tid];
        const float* w2 = &fc2w[tid * 128];
#pragma unroll 8
        for (int i = 0; i < 128; ++i) a += s_h1[i] * w2[i];
        out[b * 2 + tid] = a;
    }
}

extern "C" void kernel_launch(void* const* d_in, const int* in_sizes, int n_in,
                              void* d_out, int out_size, void* d_ws, size_t ws_size,
                              hipStream_t stream) {
    const float* x      = (const float*)d_in[0];
    const float* wih0f  = (const float*)d_in[1];
    const float* whh0f  = (const float*)d_in[2];
    const float* bih0f  = (const float*)d_in[3];
    const float* bhh0f  = (const float*)d_in[4];
    const float* wih0b  = (const float*)d_in[5];
    const float* whh0b  = (const float*)d_in[6];
    const float* bih0b  = (const float*)d_in[7];
    const float* bhh0b  = (const float*)d_in[8];
    const float* wih1f  = (const float*)d_in[9];
    const float* whh1f  = (const float*)d_in[10];
    const float* bih1f  = (const float*)d_in[11];
    const float* bhh1f  = (const float*)d_in[12];
    const float* wih1b  = (const float*)d_in[13];
    const float* whh1b  = (const float*)d_in[14];
    const float* bih1b  = (const float*)d_in[15];
    const float* bhh1b  = (const float*)d_in[16];
    const float* fc1w   = (const float*)d_in[17];
    const float* fc1b   = (const float*)d_in[18];
    const float* fc2w   = (const float*)d_in[19];
    const float* fc2b   = (const float*)d_in[20];

    const size_t Y0SZ = 134217728ull;   // y0 bf16 [512][512][256]
    const size_t HSSZ = 524288ull;      // hstate/finals f32 [512][256]
    const size_t WCSZ = 393216ull;      // wcat bf16 [768][256]
    const size_t BCSZ = 3072ull;        // bcat f32 [768]
    const size_t GX_PER_SL = 786432ull; // per sl: 2 dirs * 512 * 384 bf16 * 2B
    const size_t BASE = Y0SZ + HSSZ + WCSZ + BCSZ;

    unsigned short* y0 = (unsigned short*)d_ws;
    float*  hstate = (float*)((char*)d_ws + Y0SZ);
    unsigned short* wcat = (unsigned short*)((char*)d_ws + Y0SZ + HSSZ);
    float*  bcat   = (float*)((char*)d_ws + Y0SZ + HSSZ + WCSZ);
    unsigned short* gx0 = (unsigned short*)((char*)d_ws + BASE);
    float* out = (float*)d_out;

    const int cts[6] = {128, 64, 32, 16, 8, 4};
    int CT = 0, fused = 0;
    for (int i = 0; i < 6; ++i)
        if (BASE + 2ull * cts[i] * GX_PER_SL <= ws_size) { CT = cts[i]; fused = 1; break; }
    if (!CT)
        for (int i = 0; i < 6; ++i)
            if (BASE + (size_t)cts[i] * GX_PER_SL <= ws_size) { CT = cts[i]; break; }

    if (CT > 0) {
        unsigned short* gxb[2];
        gxb[0] = gx0;
        gxb[1] = fused ? (unsigned short*)((char*)gx0 + (size_t)CT * GX_PER_SL) : gx0;

        w_prep<<<dim3(768), dim3(256), 0, stream>>>(wih1f, wih1b, bih1f, bih1b, wcat, bcat);
        gru_l0<<<dim3(256), dim3(THREADS), 0, stream>>>(
            x, wih0f, whh0f, bih0f, bhh0f, wih0b, whh0b, bih0b, bhh0b, y0);
        const int n = Tt / CT;
        if (fused) {
            // prologue: gemm chunk 0 -> buf0
            l1_step<<<dim3(24 * CT), dim3(THREADS), 0, stream>>>(
                y0, wcat, bcat, gxb[0], gxb[0],
                whh1f, bhh1f, whh1b, bhh1b, hstate, CT, 0, 0, 1);
            for (int k = 0; k < n; ++k) {
                const int ng = (k + 1 < n) ? 24 * CT : 0;
                l1_step<<<dim3(64 + ng), dim3(THREADS), 0, stream>>>(
                    y0, wcat, bcat, gxb[k & 1], gxb[(k + 1) & 1],
                    whh1f, bhh1f, whh1b, bhh1b, hstate, CT, k + 1, 64, (k == 0) ? 1 : 0);
            }
        } else {
            for (int k = 0; k < n; ++k) {
                l1_step<<<dim3(24 * CT), dim3(THREADS), 0, stream>>>(
                    y0, wcat, bcat, gxb[0], gxb[0],
                    whh1f, bhh1f, whh1b, bhh1b, hstate, CT, k, 0, 1);
                l1_step<<<dim3(64), dim3(THREADS), 0, stream>>>(
                    y0, wcat, bcat, gxb[0], gxb[0],
                    whh1f, bhh1f, whh1b, bhh1b, hstate, CT, 0, 64, (k == 0) ? 1 : 0);
            }
        }
        fc_head<<<dim3(Bb), dim3(128), 0, stream>>>(hstate, fc1w, fc1b, fc2w, fc2b, out);
    } else {
        float* finals = (float*)((char*)d_ws + Y0SZ);
        gru_l0<<<dim3(256), dim3(THREADS), 0, stream>>>(
            x, wih0f, whh0f, bih0f, bhh0f, wih0b, whh0b, bih0b, bhh0b, y0);
        gru_l1<<<dim3(64), dim3(THREADS), 0, stream>>>(
            y0, wih1f, whh1f, bih1f, bhh1f, wih1b, whh1b, bih1b, bhh1b, finals);
        fc_head<<<dim3(Bb), dim3(128), 0, stream>>>(finals, fc1w, fc1b, fc2w, fc2b, out);
    }
}

// Round 10
// 1099.627 us; speedup vs baseline: 1.9408x; 1.0457x over previous
//
#include <hip/hip_runtime.h>
#include <stdint.h>

// GRUClassifier: 2-layer bidir GRU (H=128, T=512, B=512) + FC head.
// R10: gru_l0 x-projection de-redundancy. R9 kept a fully redundant per-lane
// x-proj (48 FMA: all 4 rows x 3 gates) because xp was folded into the MFMA
// accumulator init. Now acc init = bias only; after the shfl redistribution
// each lane adds its OWN row's x-proj (12 FMA, 1 float4 load). l1 pipeline
// verbatim R8/R9 (fused scan + next-chunk gemm, ping-pong gx buffers).

#define Tt 512
#define Bb 512
#define THREADS 512

using s16x8 = __attribute__((ext_vector_type(8))) short;  // 8 bf16 (4 VGPRs)
using f32x4 = __attribute__((ext_vector_type(4))) float;

#define MF(a, b, c) __builtin_amdgcn_mfma_f32_16x16x32_bf16((a), (b), (c), 0, 0, 0)

__device__ __forceinline__ unsigned short f2bf(float f) {
    union { float f; unsigned int u; } v; v.f = f;
    unsigned int u = v.u;
    u += 0x7fffu + ((u >> 16) & 1u);   // RNE
    return (unsigned short)(u >> 16);
}
__device__ __forceinline__ float bf2f(unsigned short h) {
    union { unsigned int u; float f; } v; v.u = ((unsigned int)h) << 16;
    return v.f;
}

__device__ __forceinline__ float fsig(float x) {
    return __builtin_amdgcn_rcpf(1.0f + __expf(-x));
}
__device__ __forceinline__ float ftanh(float x) {
    return 2.0f * __builtin_amdgcn_rcpf(1.0f + __expf(-2.0f * x)) - 1.0f;
}

// Raw workgroup barrier: drains LDS ops only; in-flight global register
// prefetch loads survive it (vmcnt not drained).
#define WG_BARRIER() asm volatile("s_waitcnt lgkmcnt(0)\n\ts_barrier" ::: "memory")

// ---------------------------------------------------------------------------
// w_prep: pack W_ih1 (both dirs) to bf16 [768][256] + bias concat [768].
// ---------------------------------------------------------------------------
__global__ void w_prep(const float* __restrict__ wihf, const float* __restrict__ wihb,
                       const float* __restrict__ bihf, const float* __restrict__ bihb,
                       unsigned short* __restrict__ wcat, float* __restrict__ bcat)
{
    const int n = blockIdx.x;   // 0..767
    const int k = threadIdx.x;  // 0..255
    const float* src = (n < 384) ? &wihf[(size_t)n * 256] : &wihb[(size_t)(n - 384) * 256];
    wcat[(size_t)n * 256 + k] = f2bf(src[k]);
    if (k == 0) bcat[n] = (n < 384) ? bihf[n] : bihb[n - 384];
}

// ---------------------------------------------------------------------------
// l1_step: fused chunk kernel (verbatim R8).
//   blocks [0,nscan): scan role, reads gx_rd. blocks [nscan,..): gemm role,
//   chunk kgemm, writes gx_wr. gx layout [(dir*CT+sl)*512 + b]*384 + gc.
// ---------------------------------------------------------------------------
__global__ __launch_bounds__(THREADS) void l1_step(
    const unsigned short* __restrict__ y0,
    const unsigned short* __restrict__ wcat,
    const float* __restrict__ bcat,
    const unsigned short* __restrict__ gx_rd,
    unsigned short* __restrict__ gx_wr,
    const float* __restrict__ whh_f, const float* __restrict__ bhh_f,
    const float* __restrict__ whh_b, const float* __restrict__ bhh_b,
    float* __restrict__ hstate,
    int CT, int kgemm, int nscan, int first)
{
    const int bid  = blockIdx.x;
    const int tid  = threadIdx.x;
    const int wave = tid >> 6;
    const int lane = tid & 63;
    const int lcol = lane & 15;
    const int quad = lane >> 4;

    __shared__ __align__(16) unsigned short lA[128][136];
    __shared__ __align__(16) unsigned short lB[128][136];
    __shared__ __align__(16) unsigned short lds_h[2][16][136];

    if (bid >= nscan) {
        // =============================== GEMM role ===========================
        int gb = bid - nscan;
        const int nt = gb % 3;  gb /= 3;
        const int bt = gb & 3;  gb >>= 2;
        const int sl = gb % CT;
        const int dir = gb / CT;
        const int s  = kgemm * CT + sl;
        const int t  = dir ? (511 - s) : s;
        const int bb = bt << 7;

        const unsigned short* Abase = y0 + ((size_t)t * 512 + bb) * 256;
        const unsigned short* Bbase = wcat + ((size_t)dir * 384 + nt * 128) * 256;

        const int r0 = (wave >> 2) * 64;   // 0 or 64
        const int c0 = (wave & 3) * 32;    // 0,32,64,96

        f32x4 acc[4][2];
#pragma unroll
        for (int ti = 0; ti < 4; ++ti)
#pragma unroll
            for (int tj = 0; tj < 2; ++tj) acc[ti][tj] = {0.f, 0.f, 0.f, 0.f};

        const int rstg = tid >> 4;         // 0..31
        const int cstg = (tid & 15) * 8;   // 0..120 (<136)

#pragma unroll
        for (int kh = 0; kh < 2; ++kh) {
            if (kh) __syncthreads();
#pragma unroll
            for (int it = 0; it < 4; ++it) {
                const int r = it * 32 + rstg;
                *(ulonglong2*)&lA[r][cstg] =
                    *(const ulonglong2*)&Abase[(size_t)r * 256 + kh * 128 + cstg];
                *(ulonglong2*)&lB[r][cstg] =
                    *(const ulonglong2*)&Bbase[(size_t)r * 256 + kh * 128 + cstg];
            }
            __syncthreads();

#pragma unroll
            for (int kk = 0; kk < 4; ++kk) {
                s16x8 af[4], bfv[2];
#pragma unroll
                for (int ti = 0; ti < 4; ++ti)
                    af[ti] = *(const s16x8*)&lA[r0 + ti * 16 + lcol][kk * 32 + quad * 8];
#pragma unroll
                for (int tj = 0; tj < 2; ++tj)
                    bfv[tj] = *(const s16x8*)&lB[c0 + tj * 16 + lcol][kk * 32 + quad * 8];
#pragma unroll
                for (int ti = 0; ti < 4; ++ti)
#pragma unroll
                    for (int tj = 0; tj < 2; ++tj)
                        acc[ti][tj] = MF(af[ti], bfv[tj], acc[ti][tj]);
            }
        }

        float bias[2];
#pragma unroll
        for (int tj = 0; tj < 2; ++tj)
            bias[tj] = bcat[dir * 384 + nt * 128 + c0 + tj * 16 + lcol];

        __syncthreads();   // fragment reads done; reuse lA as C staging

        unsigned short* lC = &lA[0][0];
#pragma unroll
        for (int ti = 0; ti < 4; ++ti)
#pragma unroll
            for (int tj = 0; tj < 2; ++tj) {
                const int col = c0 + tj * 16 + lcol;
#pragma unroll
                for (int i = 0; i < 4; ++i)
                    lC[(size_t)(r0 + ti * 16 + 4 * quad + i) * 136 + col] =
                        f2bf(acc[ti][tj][i] + bias[tj]);
            }
        __syncthreads();

        unsigned short* ob = gx_wr + ((size_t)(dir * CT + sl) * 512 + bb) * 384 + nt * 128;
#pragma unroll
        for (int it = 0; it < 4; ++it) {
            const int r = it * 32 + rstg;
            *(ulonglong2*)&ob[(size_t)r * 384 + cstg] =
                *(const ulonglong2*)&lC[(size_t)r * 136 + cstg];
        }
        return;
    }

    // ================================ SCAN role ==============================
    const int dir   = bid >> 5;
    const int chunk = bid & 31;
    const int b0    = chunk * 16;
    const int c     = 16 * wave + lcol;

    const float* whh = dir ? whh_b : whh_f;
    const float* bhh = dir ? bhh_b : bhh_f;

    const float bhr = bhh[c];
    const float bhz = bhh[128 + c];
    const float bhn = bhh[256 + c];

    s16x8 bh[3][4];
#pragma unroll
    for (int p = 0; p < 3; ++p) {
        const int nrow = p * 128 + c;
#pragma unroll
        for (int kk = 0; kk < 4; ++kk) {
            const float* src = &whh[(size_t)nrow * 128 + kk * 32 + quad * 8];
            s16x8 f;
#pragma unroll
            for (int j = 0; j < 8; ++j) f[j] = (short)f2bf(src[j]);
            bh[p][kk] = f;
        }
    }

    const unsigned short* gbase = gx_rd + (size_t)dir * CT * 512 * 384;
    auto loadGX = [&](unsigned short (&G)[12], int sl) {
        const unsigned short* gp = gbase + ((size_t)sl * 512 + b0 + 4 * quad) * 384;
#pragma unroll
        for (int g = 0; g < 3; ++g)
#pragma unroll
            for (int i = 0; i < 4; ++i)
                G[g * 4 + i] = gp[(size_t)i * 384 + g * 128 + c];
    };
    unsigned short G0[12], G1[12];
    loadGX(G0, 0);
    loadGX(G1, 1);

    float hreg[4];
    const int gb2 = tid >> 5;          // 0..15 batch row for LDS init
    const int j0  = (tid & 31) * 4;    // 0..124
    if (first) {
#pragma unroll
        for (int i = 0; i < 4; ++i) hreg[i] = 0.f;
        ushort4 z4; z4.x = 0; z4.y = 0; z4.z = 0; z4.w = 0;
        *(ushort4*)&lds_h[0][gb2][j0] = z4;
    } else {
#pragma unroll
        for (int i = 0; i < 4; ++i)
            hreg[i] = hstate[(size_t)(b0 + 4 * quad + i) * 256 + dir * 128 + c];
        ushort4 hv;
        hv.x = f2bf(hstate[(size_t)(b0 + gb2) * 256 + dir * 128 + j0 + 0]);
        hv.y = f2bf(hstate[(size_t)(b0 + gb2) * 256 + dir * 128 + j0 + 1]);
        hv.z = f2bf(hstate[(size_t)(b0 + gb2) * 256 + dir * 128 + j0 + 2]);
        hv.w = f2bf(hstate[(size_t)(b0 + gb2) * 256 + dir * 128 + j0 + 3]);
        *(ushort4*)&lds_h[0][gb2][j0] = hv;
    }
    __syncthreads();

#define L1C_STEP(S, PAR, G)                                                    \
    do {                                                                       \
        const s16x8 a0 = *(const s16x8*)&lds_h[PAR][lcol][0  + quad * 8];      \
        const s16x8 a1 = *(const s16x8*)&lds_h[PAR][lcol][32 + quad * 8];      \
        const s16x8 a2 = *(const s16x8*)&lds_h[PAR][lcol][64 + quad * 8];      \
        const s16x8 a3 = *(const s16x8*)&lds_h[PAR][lcol][96 + quad * 8];      \
        f32x4 rA = {bhr, bhr, bhr, bhr}, rB = {0.f, 0.f, 0.f, 0.f};            \
        f32x4 zA = {bhz, bhz, bhz, bhz}, zB = {0.f, 0.f, 0.f, 0.f};            \
        f32x4 nA = {bhn, bhn, bhn, bhn}, nB = {0.f, 0.f, 0.f, 0.f};            \
        rA = MF(a0, bh[0][0], rA); zA = MF(a0, bh[1][0], zA);                  \
        nA = MF(a0, bh[2][0], nA);                                             \
        rB = MF(a1, bh[0][1], rB); zB = MF(a1, bh[1][1], zB);                  \
        nB = MF(a1, bh[2][1], nB);                                             \
        rA = MF(a2, bh[0][2], rA); zA = MF(a2, bh[1][2], zA);                  \
        nA = MF(a2, bh[2][2], nA);                                             \
        rB = MF(a3, bh[0][3], rB); zB = MF(a3, bh[1][3], zB);                  \
        nB = MF(a3, bh[2][3], nB);                                             \
        _Pragma("unroll")                                                      \
        for (int i = 0; i < 4; ++i) {                                          \
            const float r = fsig(rA[i] + rB[i] + bf2f(G[i]));                  \
            const float z = fsig(zA[i] + zB[i] + bf2f(G[4 + i]));              \
            const float n = ftanh(bf2f(G[8 + i]) + r * (nA[i] + nB[i]));       \
            hreg[i] = (1.0f - z) * n + z * hreg[i];                            \
            lds_h[PAR ^ 1][4 * quad + i][c] = f2bf(hreg[i]);                   \
        }                                                                      \
        if ((S) < CT - 2) {                                                    \
            loadGX(G, (S) + 2);                                                \
        } else if ((S) == CT - 1) {                                            \
            _Pragma("unroll")                                                  \
            for (int i = 0; i < 4; ++i)                                        \
                hstate[(size_t)(b0 + 4 * quad + i) * 256 + dir * 128 + c] =    \
                    hreg[i];                                                   \
        }                                                                      \
        WG_BARRIER();                                                          \
    } while (0)

    for (int sl = 0; sl < CT; sl += 2) {
        L1C_STEP(sl,     0, G0);
        L1C_STEP(sl + 1, 1, G1);
    }
#undef L1C_STEP
}

// ---------------------------------------------------------------------------
// Fallback layer-1 (fused Gx, verbatim from passing R3) — if no CT fits.
// ---------------------------------------------------------------------------
__global__ __launch_bounds__(THREADS, 1) void gru_l1(
    const unsigned short* __restrict__ y0,
    const float* __restrict__ wih_f, const float* __restrict__ whh_f,
    const float* __restrict__ bih_f, const float* __restrict__ bhh_f,
    const float* __restrict__ wih_b, const float* __restrict__ whh_b,
    const float* __restrict__ bih_b, const float* __restrict__ bhh_b,
    float* __restrict__ finals)
{
    const int tid  = threadIdx.x;
    const int wave = tid >> 6;
    const int lane = tid & 63;
    const int lcol = lane & 15;
    const int quad = lane >> 4;
    const int dir   = blockIdx.x >> 5;
    const int b0    = (blockIdx.x & 31) * 16;
    const int c     = 16 * wave + lcol;

    const float* wih = dir ? wih_b : wih_f;
    const float* whh = dir ? whh_b : whh_f;
    const float* bih = dir ? bih_b : bih_f;
    const float* bhh = dir ? bhh_b : bhh_f;

    __shared__ __align__(16) unsigned short lds_h[2][16][136];

    const float br  = bih[c]       + bhh[c];
    const float bz  = bih[128 + c] + bhh[128 + c];
    const float bnx = bih[256 + c];
    const float bnh = bhh[256 + c];

    s16x8 bh[3][4];
    s16x8 bx[3][8];
#pragma unroll
    for (int p = 0; p < 3; ++p) {
        const int nrow = p * 128 + c;
#pragma unroll
        for (int kk = 0; kk < 4; ++kk) {
            const float* src = &whh[(size_t)nrow * 128 + kk * 32 + quad * 8];
            s16x8 f;
#pragma unroll
            for (int j = 0; j < 8; ++j) f[j] = (short)f2bf(src[j]);
            bh[p][kk] = f;
        }
#pragma unroll
        for (int kk = 0; kk < 8; ++kk) {
            const float* src = &wih[(size_t)nrow * 256 + kk * 32 + quad * 8];
            s16x8 f;
#pragma unroll
            for (int j = 0; j < 8; ++j) f[j] = (short)f2bf(src[j]);
            bx[p][kk] = f;
        }
    }

    auto loadP = [&](s16x8 (&P)[8], int t) {
        const unsigned short* pb = y0 + ((size_t)t * Bb + b0 + lcol) * 256 + quad * 8;
#pragma unroll
        for (int kk = 0; kk < 8; ++kk) P[kk] = *(const s16x8*)(pb + kk * 32);
    };
    s16x8 P0[8], P1[8];
    loadP(P0, dir ? 511 : 0);
    loadP(P1, dir ? 510 : 1);

    f32x4 accr = {br, br, br, br};
    f32x4 accz = {bz, bz, bz, bz};
    f32x4 accnx = {bnx, bnx, bnx, bnx};
#pragma unroll
    for (int kk = 0; kk < 8; ++kk) {
        accr  = MF(P0[kk], bx[0][kk], accr);
        accz  = MF(P0[kk], bx[1][kk], accz);
        accnx = MF(P0[kk], bx[2][kk], accnx);
    }
    loadP(P0, dir ? 509 : 2);

    float hreg[4] = {0.f, 0.f, 0.f, 0.f};
    for (int idx = tid; idx < 2 * 16 * 136; idx += THREADS)
        ((unsigned short*)lds_h)[idx] = 0;
    __syncthreads();

#define L1_STEP(S, PAR, PN)                                                    \
    do {                                                                       \
        const s16x8 a0 = *(const s16x8*)&lds_h[PAR][lcol][0  + quad * 8];      \
        const s16x8 a1 = *(const s16x8*)&lds_h[PAR][lcol][32 + quad * 8];      \
        const s16x8 a2 = *(const s16x8*)&lds_h[PAR][lcol][64 + quad * 8];      \
        const s16x8 a3 = *(const s16x8*)&lds_h[PAR][lcol][96 + quad * 8];      \
        f32x4 acchn = {bnh, bnh, bnh, bnh};                                    \
        accr = MF(a0, bh[0][0], accr); accz = MF(a0, bh[1][0], accz);          \
        acchn = MF(a0, bh[2][0], acchn);                                       \
        accr = MF(a1, bh[0][1], accr); accz = MF(a1, bh[1][1], accz);          \
        acchn = MF(a1, bh[2][1], acchn);                                       \
        accr = MF(a2, bh[0][2], accr); accz = MF(a2, bh[1][2], accz);          \
        acchn = MF(a2, bh[2][2], acchn);                                       \
        accr = MF(a3, bh[0][3], accr); accz = MF(a3, bh[1][3], accz);          \
        acchn = MF(a3, bh[2][3], acchn);                                       \
        _Pragma("unroll")                                                      \
        for (int i = 0; i < 4; ++i) {                                          \
            const float r = fsig(accr[i]);                                     \
            const float z = fsig(accz[i]);                                     \
            const float n = ftanh(accnx[i] + r * acchn[i]);                    \
            hreg[i] = (1.0f - z) * n + z * hreg[i];                            \
            lds_h[PAR ^ 1][4 * quad + i][c] = f2bf(hreg[i]);                   \
        }                                                                      \
        if ((S) < 511) {                                                       \
            accr = {br, br, br, br}; accz = {bz, bz, bz, bz};                  \
            accnx = {bnx, bnx, bnx, bnx};                                      \
            _Pragma("unroll")                                                  \
            for (int kk = 0; kk < 8; ++kk) {                                   \
                accr  = MF(PN[kk], bx[0][kk], accr);                           \
                accz  = MF(PN[kk], bx[1][kk], accz);                           \
                accnx = MF(PN[kk], bx[2][kk], accnx);                          \
            }                                                                  \
            int sp = (S) + 3; if (sp > 511) sp = 511;                          \
            loadP(PN, dir ? (511 - sp) : sp);                                  \
        } else {                                                               \
            _Pragma("unroll")                                                  \
            for (int i = 0; i < 4; ++i)                                        \
                finals[(size_t)(b0 + 4 * quad + i) * 256 + dir * 128 + c] =    \
                    hreg[i];                                                   \
        }                                                                      \
        WG_BARRIER();                                                          \
    } while (0)

    for (int s = 0; s < Tt; s += 2) {
        L1_STEP(s,     0, P1);
        L1_STEP(s + 1, 1, P0);
    }
#undef L1_STEP
}

// ---------------------------------------------------------------------------
// Layer 0 scan, R10: BC=4, grid 256, block 512 (8 waves). Wave w owns gate
// cols [16w,16w+16). MFMA acc init = bias only; after shfl redistribution
// each lane owns ONE element (row=quad, col=c) and adds its OWN row's
// x-projection (12 FMA, 1 float4 load) — R9's 4-row redundancy removed.
// ---------------------------------------------------------------------------
__global__ __launch_bounds__(THREADS, 1) void gru_l0(
    const float* __restrict__ x,
    const float* __restrict__ wih_f, const float* __restrict__ whh_f,
    const float* __restrict__ bih_f, const float* __restrict__ bhh_f,
    const float* __restrict__ wih_b, const float* __restrict__ whh_b,
    const float* __restrict__ bih_b, const float* __restrict__ bhh_b,
    unsigned short* __restrict__ y0)
{
    const int tid  = threadIdx.x;
    const int wave = tid >> 6;
    const int lane = tid & 63;
    const int lcol = lane & 15;
    const int quad = lane >> 4;
    const int dir   = blockIdx.x >> 7;
    const int chunk = blockIdx.x & 127;
    const int b0    = chunk * 4;
    const int c     = 16 * wave + lcol;

    const float* wih = dir ? wih_b : wih_f;
    const float* whh = dir ? whh_b : whh_f;
    const float* bih = dir ? bih_b : bih_f;
    const float* bhh = dir ? bhh_b : bhh_f;

    __shared__ __align__(16) unsigned short lds_h[2][16][136];

    const float brs  = bih[c]       + bhh[c];
    const float bzs  = bih[128 + c] + bhh[128 + c];
    const float bnxs = bih[256 + c];
    const float bnh  = bhh[256 + c];

    float wr[4], wz[4], wn[4];
#pragma unroll
    for (int f = 0; f < 4; ++f) {
        wr[f] = wih[(c)       * 4 + f];
        wz[f] = wih[(128 + c) * 4 + f];
        wn[f] = wih[(256 + c) * 4 + f];
    }

    s16x8 bh[3][4];
#pragma unroll
    for (int p = 0; p < 3; ++p) {
        const int nrow = p * 128 + c;
#pragma unroll
        for (int kk = 0; kk < 4; ++kk) {
            const float* src = &whh[(size_t)nrow * 128 + kk * 32 + quad * 8];
            s16x8 f;
#pragma unroll
            for (int j = 0; j < 8; ++j) f[j] = (short)f2bf(src[j]);
            bh[p][kk] = f;
        }
    }

    // X prefetch: each lane loads ONLY its own row (b0 + quad).
    auto loadX = [&](float4& X, int t) {
        X = *(const float4*)&x[((size_t)(b0 + quad) * Tt + t) * 4];
    };
    float4 X0, X1;
    loadX(X0, dir ? 511 : 0);
    loadX(X1, dir ? 510 : 1);

    float hmine = 0.f;   // this lane's h element: (row=quad, col=c)
    for (int idx = tid; idx < 2 * 16 * 136; idx += THREADS)
        ((unsigned short*)lds_h)[idx] = 0;
    __syncthreads();

    const int orow = tid >> 7;        // y0 store: row 0..3
    const int ocol = tid & 127;       // col 0..127

#define L0_STEP(S, PAR, XC)                                                    \
    do {                                                                       \
        const int t = dir ? (511 - (S)) : (S);                                 \
        const s16x8 a0 = *(const s16x8*)&lds_h[PAR][lcol][0  + quad * 8];      \
        const s16x8 a1 = *(const s16x8*)&lds_h[PAR][lcol][32 + quad * 8];      \
        const s16x8 a2 = *(const s16x8*)&lds_h[PAR][lcol][64 + quad * 8];      \
        const s16x8 a3 = *(const s16x8*)&lds_h[PAR][lcol][96 + quad * 8];      \
        f32x4 accr  = {brs, brs, brs, brs};                                    \
        f32x4 accz  = {bzs, bzs, bzs, bzs};                                    \
        f32x4 acchn = {bnh, bnh, bnh, bnh};                                    \
        accr = MF(a0, bh[0][0], accr); accz = MF(a0, bh[1][0], accz);          \
        acchn = MF(a0, bh[2][0], acchn);                                       \
        accr = MF(a1, bh[0][1], accr); accz = MF(a1, bh[1][1], accz);          \
        acchn = MF(a1, bh[2][1], acchn);                                       \
        accr = MF(a2, bh[0][2], accr); accz = MF(a2, bh[1][2], accz);          \
        acchn = MF(a2, bh[2][2], acchn);                                       \
        accr = MF(a3, bh[0][3], accr); accz = MF(a3, bh[1][3], accz);          \
        acchn = MF(a3, bh[2][3], acchn);                                       \
        /* own-row x-projection (independent of MFMA; scheduler overlaps) */   \
        const float xr = XC.x * wr[0] + XC.y * wr[1]                           \
                       + XC.z * wr[2] + XC.w * wr[3];                          \
        const float xz = XC.x * wz[0] + XC.y * wz[1]                           \
                       + XC.z * wz[2] + XC.w * wz[3];                          \
        const float xn = bnxs + XC.x * wn[0] + XC.y * wn[1]                    \
                       + XC.z * wn[2] + XC.w * wn[3];                          \
        /* redistribute: element (row i, col lcol) lives in lane lcol reg i */ \
        float rr0 = __shfl(accr[0], lcol), rr1 = __shfl(accr[1], lcol);        \
        float rr2 = __shfl(accr[2], lcol), rr3 = __shfl(accr[3], lcol);        \
        float zz0 = __shfl(accz[0], lcol), zz1 = __shfl(accz[1], lcol);        \
        float zz2 = __shfl(accz[2], lcol), zz3 = __shfl(accz[3], lcol);        \
        float hh0 = __shfl(acchn[0], lcol), hh1 = __shfl(acchn[1], lcol);      \
        float hh2 = __shfl(acchn[2], lcol), hh3 = __shfl(acchn[3], lcol);      \
        const float pr = quad == 0 ? rr0 : quad == 1 ? rr1 : quad == 2 ? rr2 : rr3; \
        const float pz = quad == 0 ? zz0 : quad == 1 ? zz1 : quad == 2 ? zz2 : zz3; \
        const float ph = quad == 0 ? hh0 : quad == 1 ? hh1 : quad == 2 ? hh2 : hh3; \
        {                                                                      \
            const float r = fsig(pr + xr);                                     \
            const float z = fsig(pz + xz);                                     \
            const float n = ftanh(xn + r * ph);                                \
            hmine = (1.0f - z) * n + z * hmine;                                \
            lds_h[PAR ^ 1][quad][c] = f2bf(hmine);                             \
        }                                                                      \
        if ((S) < 510) {                                                       \
            loadX(XC, dir ? (511 - ((S) + 2)) : ((S) + 2));                    \
        }                                                                      \
        WG_BARRIER();                                                          \
        {                                                                      \
            /* coalesced y0 store from the buffer just completed */            \
            y0[((size_t)t * Bb + b0 + orow) * 256 + dir * 128 + ocol] =        \
                lds_h[PAR ^ 1][orow][ocol];                                    \
        }                                                                      \
    } while (0)

    for (int s = 0; s < Tt; s += 2) {
        L0_STEP(s,     0, X0);
        L0_STEP(s + 1, 1, X1);
    }
#undef L0_STEP
}

// ---------------------------------------------------------------------------
// FC head: out = relu(finals @ fc1^T + b1) @ fc2^T + b2   [512,256]->[512,2]
// ---------------------------------------------------------------------------
__global__ __launch_bounds__(128) void fc_head(
    const float* __restrict__ finals,
    const float* __restrict__ fc1w, const float* __restrict__ fc1b,
    const float* __restrict__ fc2w, const float* __restrict__ fc2b,
    float* __restrict__ out)
{
    __shared__ float s_in[256];
    __shared__ float s_h1[128];
    const int b = blockIdx.x, tid = threadIdx.x;
    s_in[tid]       = finals[(size_t)b * 256 + tid];
    s_in[tid + 128] = finals[(size_t)b * 256 + 128 + tid];
    __syncthreads();
    float acc = fc1b[tid];
    const float* wrow = &fc1w[tid * 256];
#pragma unroll 8
    for (int i = 0; i < 256; ++i) acc += s_in[i] * wrow[i];
    s_h1[tid] = fmaxf(acc, 0.0f);
    __syncthreads();
    if (tid < 2) {
        float a = fc2b[tid];
        const float* w2 = &fc2w[tid * 128];
#pragma unroll 8
        for (int i = 0; i < 128; ++i) a += s_h1[i] * w2[i];
        out[b * 2 + tid] = a;
    }
}

extern "C" void kernel_launch(void* const* d_in, const int* in_sizes, int n_in,
                              void* d_out, int out_size, void* d_ws, size_t ws_size,
                              hipStream_t stream) {
    const float* x      = (const float*)d_in[0];
    const float* wih0f  = (const float*)d_in[1];
    const float* whh0f  = (const float*)d_in[2];
    const float* bih0f  = (const float*)d_in[3];
    const float* bhh0f  = (const float*)d_in[4];
    const float* wih0b  = (const float*)d_in[5];
    const float* whh0b  = (const float*)d_in[6];
    const float* bih0b  = (const float*)d_in[7];
    const float* bhh0b  = (const float*)d_in[8];
    const float* wih1f  = (const float*)d_in[9];
    const float* whh1f  = (const float*)d_in[10];
    const float* bih1f  = (const float*)d_in[11];
    const float* bhh1f  = (const float*)d_in[12];
    const float* wih1b  = (const float*)d_in[13];
    const float* whh1b  = (const float*)d_in[14];
    const float* bih1b  = (const float*)d_in[15];
    const float* bhh1b  = (const float*)d_in[16];
    const float* fc1w   = (const float*)d_in[17];
    const float* fc1b   = (const float*)d_in[18];
    const float* fc2w   = (const float*)d_in[19];
    const float* fc2b   = (const float*)d_in[20];

    const size_t Y0SZ = 134217728ull;   // y0 bf16 [512][512][256]
    const size_t HSSZ = 524288ull;      // hstate/finals f32 [512][256]
    const size_t WCSZ = 393216ull;      // wcat bf16 [768][256]
    const size_t BCSZ = 3072ull;        // bcat f32 [768]
    const size_t GX_PER_SL = 786432ull; // per sl: 2 dirs * 512 * 384 bf16 * 2B
    const size_t BASE = Y0SZ + HSSZ + WCSZ + BCSZ;

    unsigned short* y0 = (unsigned short*)d_ws;
    float*  hstate = (float*)((char*)d_ws + Y0SZ);
    unsigned short* wcat = (unsigned short*)((char*)d_ws + Y0SZ + HSSZ);
    float*  bcat   = (float*)((char*)d_ws + Y0SZ + HSSZ + WCSZ);
    unsigned short* gx0 = (unsigned short*)((char*)d_ws + BASE);
    float* out = (float*)d_out;

    const int cts[6] = {128, 64, 32, 16, 8, 4};
    int CT = 0, fused = 0;
    for (int i = 0; i < 6; ++i)
        if (BASE + 2ull * cts[i] * GX_PER_SL <= ws_size) { CT = cts[i]; fused = 1; break; }
    if (!CT)
        for (int i = 0; i < 6; ++i)
            if (BASE + (size_t)cts[i] * GX_PER_SL <= ws_size) { CT = cts[i]; break; }

    if (CT > 0) {
        unsigned short* gxb[2];
        gxb[0] = gx0;
        gxb[1] = fused ? (unsigned short*)((char*)gx0 + (size_t)CT * GX_PER_SL) : gx0;

        w_prep<<<dim3(768), dim3(256), 0, stream>>>(wih1f, wih1b, bih1f, bih1b, wcat, bcat);
        gru_l0<<<dim3(256), dim3(THREADS), 0, stream>>>(
            x, wih0f, whh0f, bih0f, bhh0f, wih0b, whh0b, bih0b, bhh0b, y0);
        const int n = Tt / CT;
        if (fused) {
            // prologue: gemm chunk 0 -> buf0
            l1_step<<<dim3(24 * CT), dim3(THREADS), 0, stream>>>(
                y0, wcat, bcat, gxb[0], gxb[0],
                whh1f, bhh1f, whh1b, bhh1b, hstate, CT, 0, 0, 1);
            for (int k = 0; k < n; ++k) {
                const int ng = (k + 1 < n) ? 24 * CT : 0;
                l1_step<<<dim3(64 + ng), dim3(THREADS), 0, stream>>>(
                    y0, wcat, bcat, gxb[k & 1], gxb[(k + 1) & 1],
                    whh1f, bhh1f, whh1b, bhh1b, hstate, CT, k + 1, 64, (k == 0) ? 1 : 0);
            }
        } else {
            for (int k = 0; k < n; ++k) {
                l1_step<<<dim3(24 * CT), dim3(THREADS), 0, stream>>>(
                    y0, wcat, bcat, gxb[0], gxb[0],
                    whh1f, bhh1f, whh1b, bhh1b, hstate, CT, k, 0, 1);
                l1_step<<<dim3(64), dim3(THREADS), 0, stream>>>(
                    y0, wcat, bcat, gxb[0], gxb[0],
                    whh1f, bhh1f, whh1b, bhh1b, hstate, CT, 0, 64, (k == 0) ? 1 : 0);
            }
        }
        fc_head<<<dim3(Bb), dim3(128), 0, stream>>>(hstate, fc1w, fc1b, fc2w, fc2b, out);
    } else {
        float* finals = (float*)((char*)d_ws + Y0SZ);
        gru_l0<<<dim3(256), dim3(THREADS), 0, stream>>>(
            x, wih0f, whh0f, bih0f, bhh0f, wih0b, whh0b, bih0b, bhh0b, y0);
        gru_l1<<<dim3(64), dim3(THREADS), 0, stream>>>(
            y0, wih1f, whh1f, bih1f, bhh1f, wih1b, whh1b, bih1b, bhh1b, finals);
        fc_head<<<dim3(Bb), dim3(128), 0, stream>>>(finals, fc1w, fc1b, fc2w, fc2b, out);
    }
}